// Round 7
// baseline (694.752 us; speedup 1.0000x reference)
//
#include <hip/hip_runtime.h>
#include <hip/hip_bf16.h>
#include <math.h>

#define EMBED 256
#define NF 3
#define DD 64
#define BM 256
#define BN 256
#define BK 64              // fp8 K-elements per pipeline phase
#define NKT 4              // EMBED / BK
#define MOTIF_BLOCKS 2048
#define NE 512             // embed-role blocks in k_pre
#define NMLP 1024          // mlp-role blocks in k_pre

typedef unsigned short ushort_t;
typedef unsigned char uchar_t;
typedef float f32x4 __attribute__((ext_vector_type(4)));
typedef float f32x2 __attribute__((ext_vector_type(2)));

__device__ __forceinline__ void gl2lds16(const void* g, void* l) {
    __builtin_amdgcn_global_load_lds(
        (const __attribute__((address_space(1))) unsigned int*)g,
        (__attribute__((address_space(3))) unsigned int*)l, 16, 0, 0);
}

__device__ __forceinline__ uchar_t f2fp8(float f) {
    int p = __builtin_amdgcn_cvt_pk_fp8_f32(f, f, 0, false);  // e4m3 OCP on gfx950
    return (uchar_t)(p & 0xff);
}
template<bool HI>
__device__ __forceinline__ f32x2 pk2(unsigned int w) {
    return __builtin_amdgcn_cvt_pk_f32_fp8((int)w, HI);       // .x = low byte
}

// Sum over each contiguous 16-lane row, entirely on the VALU pipe (DPP).
__device__ __forceinline__ float dpp16_red_add(float x) {
    int v;
    v = __builtin_amdgcn_update_dpp(0, __float_as_int(x), 0xB1, 0xF, 0xF, true);  // quad_perm xor1
    x += __int_as_float(v);
    v = __builtin_amdgcn_update_dpp(0, __float_as_int(x), 0x4E, 0xF, 0xF, true);  // quad_perm xor2
    x += __int_as_float(v);
    v = __builtin_amdgcn_update_dpp(0, __float_as_int(x), 0x141, 0xF, 0xF, true); // row_half_mirror
    x += __int_as_float(v);
    v = __builtin_amdgcn_update_dpp(0, __float_as_int(x), 0x140, 0xF, 0xF, true); // row_mirror
    x += __int_as_float(v);
    return x;
}

// ---------------- Kernel 1: EMBED role + MLP role in one launch (unchanged) -
__global__ __launch_bounds__(256) void k_pre(
    const float* __restrict__ x,
    const float* __restrict__ feats,
    const float* __restrict__ feat_free,
    const float* __restrict__ ks,
    const float* __restrict__ Ws,
    const float* __restrict__ bias,
    const float* __restrict__ W_free,
    const float* __restrict__ b_free,
    const float* __restrict__ W1,     // [96][64]
    const float* __restrict__ b1,     // [64]
    uchar_t* __restrict__ xnf8,       // [Npad][256] fp8 (normalized x, PRE-SCALED by 5)
    uchar_t* __restrict__ x2nf8,      // [Npad][256] fp8 (normalized x2)
    uchar_t* __restrict__ H8,         // [4][3][N][64] fp8
    float* __restrict__ acc3,         // 3 floats + ticket to zero
    int N, int Npad)
{
    int tid = threadIdx.x;

    if (blockIdx.x >= NE) {
        // ---------------- MLP role ----------------
        int lane = tid & 63;
        int gw = ((blockIdx.x - NE) * 256 + tid) >> 6;
        int nwaves = (NMLP * 256) >> 6;

        float wcol[96];
        #pragma unroll
        for (int c = 0; c < 96; ++c) wcol[c] = W1[c*64 + lane];
        float b1l = b1[lane];
        float kv0 = ks[0], kv1 = ks[1], kv2 = ks[2];

        int total = 4 * N;
        for (int unit = gw; unit < total; unit += nwaves) {
            int node = __builtin_amdgcn_readfirstlane(unit >> 2);
            int prod = __builtin_amdgcn_readfirstlane(unit & 3);
            float fc[32];
            if (prod < 3) {
                const float* P = feats + ((size_t)prod*N + node)*32;
                float red[32];
                #pragma unroll
                for (int c = 0; c < 32; ++c) { fc[c] = P[c]; red[c] = fc[c]*fc[c]; }
                // butterfly tree bit-exact vs embed role's shfl_xor chain
                #pragma unroll
                for (int st = 1; st < 32; st <<= 1)
                    #pragma unroll
                    for (int c = 0; c < 32; c += 2*st) red[c] = red[c] + red[c + st];
                float s = red[0];
                float k = (prod == 0) ? kv0 : (prod == 1) ? kv1 : kv2;
                float scale = 0.45f / (sqrtf(s) * sqrtf(fabsf(k)));
                #pragma unroll
                for (int c = 0; c < 32; ++c) fc[c] *= scale;
            } else {
                const float* P = feat_free + (size_t)node*32;
                #pragma unroll
                for (int c = 0; c < 32; ++c) fc[c] = P[c];
            }
            #pragma unroll
            for (int s = 0; s < 3; ++s) {
                float h = (s == 2) ? b1l : 0.f;
                #pragma unroll
                for (int c = 0; c < 32; ++c) h = fmaf(fc[c], wcol[s*32 + c], h);
                H8[(((size_t)prod*3 + s)*N + node)*64 + lane] = f2fp8(h);
            }
        }
        return;
    }

    // ---------------- EMBED role ----------------
    int wave = tid >> 6;
    int t    = tid & 63;
    int gtid = blockIdx.x * 256 + tid;
    int stride = NE * 256;

    for (int i = gtid; i < 4; i += stride) acc3[i] = 0.f;   // [3] = ticket
    {
        int pad = (Npad - N) * (EMBED/4);
        int* pa = (int*)(xnf8  + (size_t)N*EMBED);
        int* pb = (int*)(x2nf8 + (size_t)N*EMBED);
        for (int i = gtid; i < pad; i += stride) { pa[i] = 0; pb[i] = 0; }
    }

    __shared__ float Wl[128*65];      // rows: [i*32+c] for Ws, [96+c] for W_free
    __shared__ float xi_s[4][NF][32];
    __shared__ float ff_s[4][32];

    for (int e = tid; e < NF*DD*32; e += 256) {
        int i = e >> 11, rem = e & 2047, tr = rem >> 5, c = rem & 31;
        Wl[(i*32 + c)*65 + tr] = Ws[e];
    }
    for (int e = tid; e < DD*32; e += 256) {
        int tr = e >> 5, c = e & 31;
        Wl[(96 + c)*65 + tr] = W_free[e];
    }
    __syncthreads();                   // Wl ready; no barriers needed below

    float (*xi)[32] = xi_s[wave];
    float* ffs = ff_s[wave];
    int ngroups = (N + 3) >> 2;

    for (int grp = blockIdx.x; grp < ngroups; grp += NE) {
        int n = grp*4 + wave;
        if (n >= N) continue;          // wave-uniform

        float v[NF];
        float ffv = 0.f;
        if (t < 32) {
            #pragma unroll
            for (int i = 0; i < NF; ++i) v[i] = feats[((size_t)i*N + n)*32 + t];
            ffv = feat_free[(size_t)n*32 + t];
        } else {
            #pragma unroll
            for (int i = 0; i < NF; ++i) v[i] = 0.f;
        }

        float num[NF];
        #pragma unroll
        for (int i = 0; i < NF; ++i) {
            float s = v[i]*v[i];
            s += __shfl_xor(s, 1, 64);  s += __shfl_xor(s, 2, 64);
            s += __shfl_xor(s, 4, 64);  s += __shfl_xor(s, 8, 64);
            s += __shfl_xor(s, 16, 64);
            s = __shfl(s, 0, 64);
            float k = ks[i];
            float scale = 0.45f / (sqrtf(s) * sqrtf(fabsf(k)));
            float xv = v[i] * scale;
            if (t < 32) xi[i][t] = xv;             // wave-local LDS (lgkmcnt ordering)
            num[i] = 1.0f + k * (scale*scale*s);
        }
        if (t < 32) ffs[t] = ffv;

        float z[4];
        float zsq = 0.f;
        #pragma unroll
        for (int i = 0; i < NF; ++i) {
            float div = 0.f;
            #pragma unroll
            for (int c = 0; c < 32; ++c) {
                float d = xi[i][c] - Wl[(i*32 + c)*65 + t];
                div += d*d;
            }
            float dist = __logf(num[i] / (div + 1e-5f));
            float zz = __expf(15.5f * dist) * __cosf(dist + bias[i*DD + t]);
            z[i] = zz;
            zsq += zz*zz;
        }
        {
            float dot = 0.f;
            #pragma unroll
            for (int c = 0; c < 32; ++c) dot = fmaf(ffs[c], Wl[(96 + c)*65 + t], dot);
            float zz = __expf(15.5f * dot) * __cosf(dot + b_free[t]);
            z[3] = zz;
            zsq += zz*zz;
        }
        zsq += __shfl_xor(zsq, 1, 64);  zsq += __shfl_xor(zsq, 2, 64);
        zsq += __shfl_xor(zsq, 4, 64);  zsq += __shfl_xor(zsq, 8, 64);
        zsq += __shfl_xor(zsq, 16, 64); zsq += __shfl_xor(zsq, 32, 64);
        float iv2 = 1.0f / sqrtf(zsq);

        #pragma unroll
        for (int i = 0; i < NF; ++i) x2nf8[(size_t)n*EMBED + i*DD + t] = f2fp8(z[i]*iv2);
        x2nf8[(size_t)n*EMBED + 192 + t] = f2fp8(z[3]*iv2);

        float xv[4];
        float s1 = 0.f;
        #pragma unroll
        for (int q = 0; q < 4; ++q) { xv[q] = x[(size_t)n*EMBED + q*64 + t]; s1 += xv[q]*xv[q]; }
        s1 += __shfl_xor(s1, 1, 64);  s1 += __shfl_xor(s1, 2, 64);
        s1 += __shfl_xor(s1, 4, 64);  s1 += __shfl_xor(s1, 8, 64);
        s1 += __shfl_xor(s1, 16, 64); s1 += __shfl_xor(s1, 32, 64);
        float iv1 = 5.0f / sqrtf(s1);          // pre-scale by 5 (1/TEMP)
        #pragma unroll
        for (int q = 0; q < 4; ++q) xnf8[(size_t)n*EMBED + q*64 + t] = f2fp8(xv[q]*iv1);
    }
}

// ---------------- Kernel 2: FUSED motif + 256^2 8-wave pipelined GEMM -------
// Round 7: sim tile 128^2/4-wave -> 256^2/8-wave (m198/m201 regime: the 128^2
// 2-barrier structure ceilings at ~900 TF; 256^2 quadruples MFMA per barrier
// interval 16->64/wave and halves staged bytes + epilogue VALU per output).
// Same verified swizzle (sc = c ^ ((r>>1)&3)), counted vmcnt(4), fragment
// mapping; LDS 64KB double-buffered -> 2 blocks/CU.
__global__ __launch_bounds__(512, 4) void k_fused(
    const uchar_t* __restrict__ xn, const uchar_t* __restrict__ x2n,
    const uchar_t* __restrict__ H,        // [4][3][N][64] fp8
    const int* __restrict__ motif,        // [3][M]
    const int* __restrict__ neg_uv,       // [2][M]
    const float* __restrict__ W2,
    const float* __restrict__ b2,
    float* __restrict__ rowpart,          // [nb][Npad]  (pcol-indexed partials)
    float* __restrict__ colpart,          // [nb][Npad]  (prow-indexed partials)
    float* __restrict__ pos,
    float* __restrict__ partials,         // [MOTIF_BLOCKS]
    int N, int Npad, int nb, int M)
{
    __shared__ __align__(16) uchar_t smem[2*(BM*BK + BN*BK)];   // 65536B

    if (blockIdx.x < MOTIF_BLOCKS) {
        // ---------------- motif path (8-wave variant) ----------------
        float* wred = (float*)smem;
        int lane = threadIdx.x & 63;
        int sub  = lane >> 3;
        int ch   = (lane & 7) * 8;
        int caseId = blockIdx.x & 7;
        int rank   = (blockIdx.x >> 3) * 8 + (threadIdx.x >> 6);   // 0..2047
        int prod  = caseId >> 1;
        int isneg = caseId & 1;
        const uchar_t* Hu = H + ((size_t)prod*3 + 0)*N*64;
        const uchar_t* Hv = H + ((size_t)prod*3 + 1)*N*64;
        const uchar_t* Hw = H + ((size_t)prod*3 + 2)*N*64;
        const int* iu = isneg ? neg_uv       : motif;
        const int* iv = isneg ? (neg_uv + M) : (motif + M);
        const int* iw = motif + 2*M;

        float w2c[8];
        #pragma unroll
        for (int c = 0; c < 8; ++c) w2c[c] = W2[ch + c];
        float b2v = b2[0];

        float accl = 0.f;
        #pragma unroll 2
        for (int r0 = rank*8; r0 < M; r0 += 16384) {
            int r = r0 + sub;
            bool ok = (r < M);
            int rc = ok ? r : 0;
            int u = iu[rc], v = iv[rc], w = iw[rc];
            uint2 du = *(const uint2*)&Hu[(size_t)u*64 + ch];
            uint2 dv = *(const uint2*)&Hv[(size_t)v*64 + ch];
            uint2 dw = *(const uint2*)&Hw[(size_t)w*64 + ch];
            float pl = 0.f;
            {
                f32x2 s;
                s = pk2<false>(du.x) + pk2<false>(dv.x) + pk2<false>(dw.x);
                pl = fmaf(fmaxf(s.x,0.f), w2c[0], pl);  pl = fmaf(fmaxf(s.y,0.f), w2c[1], pl);
                s = pk2<true>(du.x) + pk2<true>(dv.x) + pk2<true>(dw.x);
                pl = fmaf(fmaxf(s.x,0.f), w2c[2], pl);  pl = fmaf(fmaxf(s.y,0.f), w2c[3], pl);
                s = pk2<false>(du.y) + pk2<false>(dv.y) + pk2<false>(dw.y);
                pl = fmaf(fmaxf(s.x,0.f), w2c[4], pl);  pl = fmaf(fmaxf(s.y,0.f), w2c[5], pl);
                s = pk2<true>(du.y) + pk2<true>(dv.y) + pk2<true>(dw.y);
                pl = fmaf(fmaxf(s.x,0.f), w2c[6], pl);  pl = fmaf(fmaxf(s.y,0.f), w2c[7], pl);
            }
            pl += __shfl_xor(pl, 1, 64);
            pl += __shfl_xor(pl, 2, 64);
            pl += __shfl_xor(pl, 4, 64);
            float logit = pl + b2v;
            float z = isneg ? -logit : logit;
            float sp = fmaxf(-z, 0.f) + __logf(1.f + __expf(-fabsf(z)));
            accl -= ok ? sp : 0.f;
        }
        #pragma unroll
        for (int m = 1; m < 64; m <<= 1) accl += __shfl_xor(accl, m, 64);

        if (lane == 0) wred[threadIdx.x >> 6] = accl;
        __syncthreads();
        if (threadIdx.x == 0) {
            float s = 0.f;
            #pragma unroll
            for (int q = 0; q < 8; ++q) s += wred[q];
            partials[blockIdx.x] = s * 0.125f;    // 8 lanes per row overcount
        }
        return;
    }

    // ---------------- sim path ----------------
    int tid  = threadIdx.x;
    int lane = tid & 63;
    int w    = tid >> 6;                  // 0..7
    int wr   = w >> 2, wc = w & 3;        // 2 x 4 wave grid
    int quad = lane >> 4, l15 = lane & 15;

    int pid = blockIdx.x - MOTIF_BLOCKS;
    // bijective XCD swizzle (m204)
    int nwg = nb * nb;
    int qq = nwg >> 3, rr = nwg & 7;
    int xcd = pid & 7, idx = pid >> 3;
    int wg = (xcd < rr ? xcd*(qq+1) : rr*(qq+1) + (xcd-rr)*qq) + idx;

    int per_group = 8 * nb;
    int group = wg / per_group;
    int rem = wg - group * per_group;
    int rowspan = min(8, nb - group * 8);
    int prow = group * 8 + rem % rowspan;
    int pcol = rem / rowspan;
    int row0 = prow * BM, col0 = pcol * BN;

    f32x4 acc[8][4];
    #pragma unroll
    for (int i = 0; i < 8; ++i)
        #pragma unroll
        for (int j = 0; j < 4; ++j) acc[i][j] = (f32x4){0.f,0.f,0.f,0.f};

    auto stage = [&](int t) {
        uchar_t* A = smem + (t & 1) * (BM*BK + BN*BK);
        uchar_t* B = A + BM*BK;
        int k0 = t * BK;
        #pragma unroll
        for (int i = 0; i < 2; ++i) {
            int slot = i*512 + tid;          // slot = r*4 + c, 1024 slots per tile
            int r = slot >> 2, c = slot & 3;
            int sc = c ^ ((r >> 1) & 3);
            gl2lds16(xn  + (size_t)(row0 + r)*EMBED + k0 + sc*16, &A[slot*16]);
            gl2lds16(x2n + (size_t)(col0 + r)*EMBED + k0 + sc*16, &B[slot*16]);
        }
    };

    stage(0);                                 // 4 loads/thread in flight
    stage(1);                                 // 8 in flight

    #pragma unroll
    for (int kt = 0; kt < NKT; ++kt) {
        // counted wait: stage(kt) complete, stage(kt+1) may stay in flight
        if (kt == NKT-1) asm volatile("s_waitcnt vmcnt(0)" ::: "memory");
        else             asm volatile("s_waitcnt vmcnt(4)" ::: "memory");
        __builtin_amdgcn_s_barrier();         // buf(kt&1) globally ready

        const uchar_t* A = smem + (kt & 1) * (BM*BK + BN*BK);
        const uchar_t* B = A + BM*BK;
        #pragma unroll
        for (int s = 0; s < 2; ++s) {        // 2 k-steps of K=32
            long a[8], b[4];
            int cq = s*2 + (quad >> 1);
            int h8 = (quad & 1) * 8;
            #pragma unroll
            for (int ti = 0; ti < 8; ++ti) {
                int ra = wr*128 + ti*16 + l15;
                a[ti] = *(const long*)&A[ra*BK + ((cq ^ ((ra >> 1) & 3)) << 4) + h8];
            }
            #pragma unroll
            for (int tj = 0; tj < 4; ++tj) {
                int rb = wc*64 + tj*16 + l15;
                b[tj] = *(const long*)&B[rb*BK + ((cq ^ ((rb >> 1) & 3)) << 4) + h8];
            }
            __builtin_amdgcn_s_setprio(1);
            #pragma unroll
            for (int ti = 0; ti < 8; ++ti)
                #pragma unroll
                for (int tj = 0; tj < 4; ++tj)
                    acc[ti][tj] = __builtin_amdgcn_mfma_f32_16x16x32_fp8_fp8(a[ti], b[tj], acc[ti][tj], 0, 0, 0);
            __builtin_amdgcn_s_setprio(0);
        }
        if (kt + 2 < NKT) {
            __builtin_amdgcn_s_barrier();     // all waves done reading buf(kt&1)
            stage(kt + 2);                    // overwrite it for phase kt+2
        }
    }
    __syncthreads();                          // full drain once, before reuse

    // ---- fused single-pass epilogue ----
    float* rsum_s = (float*)smem;             // [4][BM]  indexed by wc
    float* csum_s = rsum_s + 4*BM;            // [2][BN]  indexed by wr

    bool edge = (prow == nb-1) || (pcol == nb-1);
    float csv[4] = {0.f, 0.f, 0.f, 0.f};

    if (!edge) {
        // interior: no bounds checks. gi==gj solutions (derivation r7):
        // l15==quad*4+r, wr*8+ti == wc*4+tj  =>  wr==wc>>1, ti==(wc&1)*4+tj.
        bool diagb = (prow == pcol) && (wr == (wc >> 1));
        #pragma unroll
        for (int ti = 0; ti < 8; ++ti) {
            #pragma unroll
            for (int r = 0; r < 4; ++r) {
                float rs = 0.f;
                #pragma unroll
                for (int tj = 0; tj < 4; ++tj) {
                    float e = __expf(acc[ti][tj][r]);
                    rs += e;
                    csv[tj] += e;
                    if (diagb && ti == (wc & 1)*4 + tj && l15 == quad*4 + r)
                        pos[row0 + wr*128 + ti*16 + quad*4 + r] = e;
                }
                rs = dpp16_red_add(rs);
                if (l15 == 0) rsum_s[wc*BM + wr*128 + ti*16 + quad*4 + r] = rs;
            }
        }
    } else {
        #pragma unroll
        for (int ti = 0; ti < 8; ++ti) {
            #pragma unroll
            for (int r = 0; r < 4; ++r) {
                int gi = row0 + wr*128 + ti*16 + quad*4 + r;
                float rs = 0.f;
                #pragma unroll
                for (int tj = 0; tj < 4; ++tj) {
                    int gj = col0 + wc*64 + tj*16 + l15;
                    float e = 0.f;
                    if (gi < N && gj < N) {
                        e = __expf(acc[ti][tj][r]);
                        if (gi == gj) pos[gi] = e;
                    }
                    rs += e;
                    csv[tj] += e;
                }
                rs = dpp16_red_add(rs);
                if (l15 == 0) rsum_s[wc*BM + wr*128 + ti*16 + quad*4 + r] = rs;
            }
        }
    }
    #pragma unroll
    for (int tj = 0; tj < 4; ++tj) {
        float cs = csv[tj];
        cs += __shfl_xor(cs, 16, 64);
        cs += __shfl_xor(cs, 32, 64);
        if (lane < 16) csum_s[wr*BN + wc*64 + tj*16 + lane] = cs;
    }
    __syncthreads();
    if (tid < BM) {
        rowpart[(size_t)pcol*Npad + row0 + tid] =
            rsum_s[tid] + rsum_s[BM + tid] + rsum_s[2*BM + tid] + rsum_s[3*BM + tid];
        colpart[(size_t)prow*Npad + col0 + tid] = csum_s[tid] + csum_s[BN + tid];
    }
}

// ---------------- Kernel 3: log-reduction + ticket finalize -----------------
__global__ __launch_bounds__(256) void k_final(
    const float* __restrict__ rowpart, const float* __restrict__ colpart,
    const float* __restrict__ pos, const float* __restrict__ partials,
    float* __restrict__ acc3, int* __restrict__ ticket,
    float* __restrict__ out, int N, int Npad, int nb, int nparts, int M)
{
    __shared__ float red1[256], red2[256], red3[256];
    int t = threadIdx.x;
    int g = blockIdx.x * 256 + t;
    int stride = gridDim.x * 256;
    float l1 = 0.f, l2 = 0.f, mo = 0.f;
    for (int i = g; i < N; i += stride) {
        float rs = 0.f, cs = 0.f;
        for (int p = 0; p < nb; ++p) {
            rs += rowpart[(size_t)p*Npad + i];    // coalesced across threads
            cs += colpart[(size_t)p*Npad + i];
        }
        float pv = pos[i];
        l1 += __logf((cs - pv) / pv);
        l2 += __logf((rs - pv) / pv);
    }
    for (int i = g; i < nparts; i += stride) mo += partials[i];
    red1[t] = l1; red2[t] = l2; red3[t] = mo; __syncthreads();
    for (int s = 128; s > 0; s >>= 1) {
        if (t < s) { red1[t] += red1[t+s]; red2[t] += red2[t+s]; red3[t] += red3[t+s]; }
        __syncthreads();
    }
    if (t == 0) {
        atomicAdd(&acc3[0], red1[0]);
        atomicAdd(&acc3[1], red2[0]);
        atomicAdd(&acc3[2], red3[0]);
        __threadfence();                          // adds visible before ticket
        int old = atomicAdd(ticket, 1);
        if (old == (int)gridDim.x - 1) {
            float a0 = atomicAdd(&acc3[0], 0.f);
            float a1 = atomicAdd(&acc3[1], 0.f);
            float a2 = atomicAdd(&acc3[2], 0.f);
            float cl = 0.5f * (a0 + a1) / (float)N;
            out[0] = cl - a2 / (float)M;
        }
    }
}

extern "C" void kernel_launch(void* const* d_in, const int* in_sizes, int n_in,
                              void* d_out, int out_size, void* d_ws, size_t ws_size,
                              hipStream_t stream)
{
    const float* x         = (const float*)d_in[0];
    const float* feats     = (const float*)d_in[1];
    const float* feat_free = (const float*)d_in[2];
    const float* ks        = (const float*)d_in[3];
    const float* Ws        = (const float*)d_in[4];
    const float* bias      = (const float*)d_in[5];
    const float* W_free    = (const float*)d_in[6];
    const float* b_free    = (const float*)d_in[7];
    const float* W1        = (const float*)d_in[8];
    const float* b1        = (const float*)d_in[9];
    const float* W2        = (const float*)d_in[10];
    const float* b2        = (const float*)d_in[11];
    const int*   motif     = (const int*)d_in[12];
    const int*   neg_uv    = (const int*)d_in[13];
    int N = in_sizes[0] / EMBED;          // 10000
    int M = in_sizes[13] / 2;             // 50000
    int nb = (N + BM - 1) / BM;           // 40
    int Npad = nb * BM;                   // 10240

    uchar_t* xnf8  = (uchar_t*)d_ws;                       // Npad*256 fp8
    uchar_t* x2nf8 = xnf8 + (size_t)Npad*EMBED;            // Npad*256 fp8
    uchar_t* H8    = x2nf8 + (size_t)Npad*EMBED;           // 12*N*64 fp8
    float* posv   = (float*)(H8 + (size_t)12*N*64);        // N
    float* acc3   = posv + N;                              // 3 + ticket
    int*   ticket = (int*)(acc3 + 3);
    float* partials = acc3 + 4;                            // MOTIF_BLOCKS
    float* rowpart  = partials + MOTIF_BLOCKS;             // nb*Npad
    float* colpart  = rowpart + (size_t)nb*Npad;           // nb*Npad

    k_pre<<<NE + NMLP, 256, 0, stream>>>(x, feats, feat_free, ks, Ws, bias,
                                         W_free, b_free, W1, b1,
                                         xnf8, x2nf8, H8, acc3, N, Npad);
    k_fused<<<MOTIF_BLOCKS + nb*nb, 512, 0, stream>>>(xnf8, x2nf8, H8, motif, neg_uv,
                                                      W2, b2, rowpart, colpart, posv,
                                                      partials, N, Npad, nb, M);
    k_final<<<256, 256, 0, stream>>>(rowpart, colpart, posv, partials, acc3, ticket,
                                     (float*)d_out, N, Npad, nb, MOTIF_BLOCKS, M);
}

// Round 8
// 251.671 us; speedup vs baseline: 2.7606x; 2.7606x over previous
//
#include <hip/hip_runtime.h>
#include <hip/hip_bf16.h>
#include <math.h>

#define EMBED 256
#define NF 3
#define DD 64
#define BM 256
#define BN 256
#define BK 64              // fp8 K-elements per pipeline phase
#define NKT 4              // EMBED / BK
#define TILE (BM*BK + BN*BK)   // 32768 B per K-tile (A+B)
#define MOTIF_BLOCKS 2048
#define NE 512             // embed-role blocks in k_pre
#define NMLP 1024          // mlp-role blocks in k_pre

typedef unsigned short ushort_t;
typedef unsigned char uchar_t;
typedef float f32x4 __attribute__((ext_vector_type(4)));
typedef float f32x2 __attribute__((ext_vector_type(2)));

__device__ __forceinline__ void gl2lds16(const void* g, void* l) {
    __builtin_amdgcn_global_load_lds(
        (const __attribute__((address_space(1))) unsigned int*)g,
        (__attribute__((address_space(3))) unsigned int*)l, 16, 0, 0);
}

__device__ __forceinline__ uchar_t f2fp8(float f) {
    int p = __builtin_amdgcn_cvt_pk_fp8_f32(f, f, 0, false);  // e4m3 OCP on gfx950
    return (uchar_t)(p & 0xff);
}
template<bool HI>
__device__ __forceinline__ f32x2 pk2(unsigned int w) {
    return __builtin_amdgcn_cvt_pk_f32_fp8((int)w, HI);       // .x = low byte
}

// Sum over each contiguous 16-lane row, entirely on the VALU pipe (DPP).
__device__ __forceinline__ float dpp16_red_add(float x) {
    int v;
    v = __builtin_amdgcn_update_dpp(0, __float_as_int(x), 0xB1, 0xF, 0xF, true);  // quad_perm xor1
    x += __int_as_float(v);
    v = __builtin_amdgcn_update_dpp(0, __float_as_int(x), 0x4E, 0xF, 0xF, true);  // quad_perm xor2
    x += __int_as_float(v);
    v = __builtin_amdgcn_update_dpp(0, __float_as_int(x), 0x141, 0xF, 0xF, true); // row_half_mirror
    x += __int_as_float(v);
    v = __builtin_amdgcn_update_dpp(0, __float_as_int(x), 0x140, 0xF, 0xF, true); // row_mirror
    x += __int_as_float(v);
    return x;
}

// ---------------- Kernel 1: EMBED role + MLP role in one launch (unchanged) -
__global__ __launch_bounds__(256) void k_pre(
    const float* __restrict__ x,
    const float* __restrict__ feats,
    const float* __restrict__ feat_free,
    const float* __restrict__ ks,
    const float* __restrict__ Ws,
    const float* __restrict__ bias,
    const float* __restrict__ W_free,
    const float* __restrict__ b_free,
    const float* __restrict__ W1,     // [96][64]
    const float* __restrict__ b1,     // [64]
    uchar_t* __restrict__ xnf8,       // [Npad][256] fp8 (normalized x, PRE-SCALED by 5)
    uchar_t* __restrict__ x2nf8,      // [Npad][256] fp8 (normalized x2)
    uchar_t* __restrict__ H8,         // [4][3][N][64] fp8
    float* __restrict__ acc3,         // 3 floats + ticket to zero
    int N, int Npad)
{
    int tid = threadIdx.x;

    if (blockIdx.x >= NE) {
        // ---------------- MLP role ----------------
        int lane = tid & 63;
        int gw = ((blockIdx.x - NE) * 256 + tid) >> 6;
        int nwaves = (NMLP * 256) >> 6;

        float wcol[96];
        #pragma unroll
        for (int c = 0; c < 96; ++c) wcol[c] = W1[c*64 + lane];
        float b1l = b1[lane];
        float kv0 = ks[0], kv1 = ks[1], kv2 = ks[2];

        int total = 4 * N;
        for (int unit = gw; unit < total; unit += nwaves) {
            int node = __builtin_amdgcn_readfirstlane(unit >> 2);
            int prod = __builtin_amdgcn_readfirstlane(unit & 3);
            float fc[32];
            if (prod < 3) {
                const float* P = feats + ((size_t)prod*N + node)*32;
                float red[32];
                #pragma unroll
                for (int c = 0; c < 32; ++c) { fc[c] = P[c]; red[c] = fc[c]*fc[c]; }
                // butterfly tree bit-exact vs embed role's shfl_xor chain
                #pragma unroll
                for (int st = 1; st < 32; st <<= 1)
                    #pragma unroll
                    for (int c = 0; c < 32; c += 2*st) red[c] = red[c] + red[c + st];
                float s = red[0];
                float k = (prod == 0) ? kv0 : (prod == 1) ? kv1 : kv2;
                float scale = 0.45f / (sqrtf(s) * sqrtf(fabsf(k)));
                #pragma unroll
                for (int c = 0; c < 32; ++c) fc[c] *= scale;
            } else {
                const float* P = feat_free + (size_t)node*32;
                #pragma unroll
                for (int c = 0; c < 32; ++c) fc[c] = P[c];
            }
            #pragma unroll
            for (int s = 0; s < 3; ++s) {
                float h = (s == 2) ? b1l : 0.f;
                #pragma unroll
                for (int c = 0; c < 32; ++c) h = fmaf(fc[c], wcol[s*32 + c], h);
                H8[(((size_t)prod*3 + s)*N + node)*64 + lane] = f2fp8(h);
            }
        }
        return;
    }

    // ---------------- EMBED role ----------------
    int wave = tid >> 6;
    int t    = tid & 63;
    int gtid = blockIdx.x * 256 + tid;
    int stride = NE * 256;

    for (int i = gtid; i < 4; i += stride) acc3[i] = 0.f;   // [3] = ticket
    {
        int pad = (Npad - N) * (EMBED/4);
        int* pa = (int*)(xnf8  + (size_t)N*EMBED);
        int* pb = (int*)(x2nf8 + (size_t)N*EMBED);
        for (int i = gtid; i < pad; i += stride) { pa[i] = 0; pb[i] = 0; }
    }

    __shared__ float Wl[128*65];      // rows: [i*32+c] for Ws, [96+c] for W_free
    __shared__ float xi_s[4][NF][32];
    __shared__ float ff_s[4][32];

    for (int e = tid; e < NF*DD*32; e += 256) {
        int i = e >> 11, rem = e & 2047, tr = rem >> 5, c = rem & 31;
        Wl[(i*32 + c)*65 + tr] = Ws[e];
    }
    for (int e = tid; e < DD*32; e += 256) {
        int tr = e >> 5, c = e & 31;
        Wl[(96 + c)*65 + tr] = W_free[e];
    }
    __syncthreads();                   // Wl ready; no barriers needed below

    float (*xi)[32] = xi_s[wave];
    float* ffs = ff_s[wave];
    int ngroups = (N + 3) >> 2;

    for (int grp = blockIdx.x; grp < ngroups; grp += NE) {
        int n = grp*4 + wave;
        if (n >= N) continue;          // wave-uniform

        float v[NF];
        float ffv = 0.f;
        if (t < 32) {
            #pragma unroll
            for (int i = 0; i < NF; ++i) v[i] = feats[((size_t)i*N + n)*32 + t];
            ffv = feat_free[(size_t)n*32 + t];
        } else {
            #pragma unroll
            for (int i = 0; i < NF; ++i) v[i] = 0.f;
        }

        float num[NF];
        #pragma unroll
        for (int i = 0; i < NF; ++i) {
            float s = v[i]*v[i];
            s += __shfl_xor(s, 1, 64);  s += __shfl_xor(s, 2, 64);
            s += __shfl_xor(s, 4, 64);  s += __shfl_xor(s, 8, 64);
            s += __shfl_xor(s, 16, 64);
            s = __shfl(s, 0, 64);
            float k = ks[i];
            float scale = 0.45f / (sqrtf(s) * sqrtf(fabsf(k)));
            float xv = v[i] * scale;
            if (t < 32) xi[i][t] = xv;             // wave-local LDS (lgkmcnt ordering)
            num[i] = 1.0f + k * (scale*scale*s);
        }
        if (t < 32) ffs[t] = ffv;

        float z[4];
        float zsq = 0.f;
        #pragma unroll
        for (int i = 0; i < NF; ++i) {
            float div = 0.f;
            #pragma unroll
            for (int c = 0; c < 32; ++c) {
                float d = xi[i][c] - Wl[(i*32 + c)*65 + t];
                div += d*d;
            }
            float dist = __logf(num[i] / (div + 1e-5f));
            float zz = __expf(15.5f * dist) * __cosf(dist + bias[i*DD + t]);
            z[i] = zz;
            zsq += zz*zz;
        }
        {
            float dot = 0.f;
            #pragma unroll
            for (int c = 0; c < 32; ++c) dot = fmaf(ffs[c], Wl[(96 + c)*65 + t], dot);
            float zz = __expf(15.5f * dot) * __cosf(dot + b_free[t]);
            z[3] = zz;
            zsq += zz*zz;
        }
        zsq += __shfl_xor(zsq, 1, 64);  zsq += __shfl_xor(zsq, 2, 64);
        zsq += __shfl_xor(zsq, 4, 64);  zsq += __shfl_xor(zsq, 8, 64);
        zsq += __shfl_xor(zsq, 16, 64); zsq += __shfl_xor(zsq, 32, 64);
        float iv2 = 1.0f / sqrtf(zsq);

        #pragma unroll
        for (int i = 0; i < NF; ++i) x2nf8[(size_t)n*EMBED + i*DD + t] = f2fp8(z[i]*iv2);
        x2nf8[(size_t)n*EMBED + 192 + t] = f2fp8(z[3]*iv2);

        float xv[4];
        float s1 = 0.f;
        #pragma unroll
        for (int q = 0; q < 4; ++q) { xv[q] = x[(size_t)n*EMBED + q*64 + t]; s1 += xv[q]*xv[q]; }
        s1 += __shfl_xor(s1, 1, 64);  s1 += __shfl_xor(s1, 2, 64);
        s1 += __shfl_xor(s1, 4, 64);  s1 += __shfl_xor(s1, 8, 64);
        s1 += __shfl_xor(s1, 16, 64); s1 += __shfl_xor(s1, 32, 64);
        float iv1 = 5.0f / sqrtf(s1);          // pre-scale by 5 (1/TEMP)
        #pragma unroll
        for (int q = 0; q < 4; ++q) xnf8[(size_t)n*EMBED + q*64 + t] = f2fp8(xv[q]*iv1);
    }
}

// ---------------- Kernel 2: FUSED motif + 256^2 8-wave 8-PHASE GEMM --------
// Round 8. r7 proved the 256^2 index math correct (absmax 0) but
// __launch_bounds__(512,4) capped VGPR at 64 -> full acc spill (1.27GB
// scratch writes). Fixes: (512,2) -> 256-VGPR budget, acc[8][4]=128 fits.
// K-loop rebuilt as T3+T4 phase interleave: TRIPLE-buffered LDS (3x32KB;
// occupancy is VGPR-bound at 1 block/CU so extra LDS is free) makes
// stage(kt+2) always write a buffer nobody reads -> phase barriers are
// performance shaping only, no race possible. Per phase: {ds_read subtile,
// 1 staging load, barrier, 16-MFMA cluster in setprio(1)}. vmcnt(4) counted
// protocol identical to the verified r6 scheme.
__global__ __launch_bounds__(512, 2) void k_fused(
    const uchar_t* __restrict__ xn, const uchar_t* __restrict__ x2n,
    const uchar_t* __restrict__ H,        // [4][3][N][64] fp8
    const int* __restrict__ motif,        // [3][M]
    const int* __restrict__ neg_uv,       // [2][M]
    const float* __restrict__ W2,
    const float* __restrict__ b2,
    float* __restrict__ rowpart,          // [nb][Npad]  (pcol-indexed partials)
    float* __restrict__ colpart,          // [nb][Npad]  (prow-indexed partials)
    float* __restrict__ pos,
    float* __restrict__ partials,         // [MOTIF_BLOCKS]
    int N, int Npad, int nb, int M)
{
    __shared__ __align__(16) uchar_t smem[3*TILE];   // 98304B, triple buffer

    if (blockIdx.x < MOTIF_BLOCKS) {
        // ---------------- motif path (8-wave, verified r7) ----------------
        float* wred = (float*)smem;
        int lane = threadIdx.x & 63;
        int sub  = lane >> 3;
        int ch   = (lane & 7) * 8;
        int caseId = blockIdx.x & 7;
        int rank   = (blockIdx.x >> 3) * 8 + (threadIdx.x >> 6);   // 0..2047
        int prod  = caseId >> 1;
        int isneg = caseId & 1;
        const uchar_t* Hu = H + ((size_t)prod*3 + 0)*N*64;
        const uchar_t* Hv = H + ((size_t)prod*3 + 1)*N*64;
        const uchar_t* Hw = H + ((size_t)prod*3 + 2)*N*64;
        const int* iu = isneg ? neg_uv       : motif;
        const int* iv = isneg ? (neg_uv + M) : (motif + M);
        const int* iw = motif + 2*M;

        float w2c[8];
        #pragma unroll
        for (int c = 0; c < 8; ++c) w2c[c] = W2[ch + c];
        float b2v = b2[0];

        float accl = 0.f;
        #pragma unroll 2
        for (int r0 = rank*8; r0 < M; r0 += 16384) {
            int r = r0 + sub;
            bool ok = (r < M);
            int rc = ok ? r : 0;
            int u = iu[rc], v = iv[rc], w = iw[rc];
            uint2 du = *(const uint2*)&Hu[(size_t)u*64 + ch];
            uint2 dv = *(const uint2*)&Hv[(size_t)v*64 + ch];
            uint2 dw = *(const uint2*)&Hw[(size_t)w*64 + ch];
            float pl = 0.f;
            {
                f32x2 s;
                s = pk2<false>(du.x) + pk2<false>(dv.x) + pk2<false>(dw.x);
                pl = fmaf(fmaxf(s.x,0.f), w2c[0], pl);  pl = fmaf(fmaxf(s.y,0.f), w2c[1], pl);
                s = pk2<true>(du.x) + pk2<true>(dv.x) + pk2<true>(dw.x);
                pl = fmaf(fmaxf(s.x,0.f), w2c[2], pl);  pl = fmaf(fmaxf(s.y,0.f), w2c[3], pl);
                s = pk2<false>(du.y) + pk2<false>(dv.y) + pk2<false>(dw.y);
                pl = fmaf(fmaxf(s.x,0.f), w2c[4], pl);  pl = fmaf(fmaxf(s.y,0.f), w2c[5], pl);
                s = pk2<true>(du.y) + pk2<true>(dv.y) + pk2<true>(dw.y);
                pl = fmaf(fmaxf(s.x,0.f), w2c[6], pl);  pl = fmaf(fmaxf(s.y,0.f), w2c[7], pl);
            }
            pl += __shfl_xor(pl, 1, 64);
            pl += __shfl_xor(pl, 2, 64);
            pl += __shfl_xor(pl, 4, 64);
            float logit = pl + b2v;
            float z = isneg ? -logit : logit;
            float sp = fmaxf(-z, 0.f) + __logf(1.f + __expf(-fabsf(z)));
            accl -= ok ? sp : 0.f;
        }
        #pragma unroll
        for (int m = 1; m < 64; m <<= 1) accl += __shfl_xor(accl, m, 64);

        if (lane == 0) wred[threadIdx.x >> 6] = accl;
        __syncthreads();
        if (threadIdx.x == 0) {
            float s = 0.f;
            #pragma unroll
            for (int q = 0; q < 8; ++q) s += wred[q];
            partials[blockIdx.x] = s * 0.125f;
        }
        return;
    }

    // ---------------- sim path ----------------
    int tid  = threadIdx.x;
    int lane = tid & 63;
    int w    = tid >> 6;                  // 0..7
    int wr   = w >> 2, wc = w & 3;        // 2 x 4 wave grid
    int quad = lane >> 4, l15 = lane & 15;

    int pid = blockIdx.x - MOTIF_BLOCKS;
    // bijective XCD swizzle (m204)
    int nwg = nb * nb;
    int qq = nwg >> 3, rr = nwg & 7;
    int xcd = pid & 7, idx = pid >> 3;
    int wg = (xcd < rr ? xcd*(qq+1) : rr*(qq+1) + (xcd-rr)*qq) + idx;

    int per_group = 8 * nb;
    int group = wg / per_group;
    int rem = wg - group * per_group;
    int rowspan = min(8, nb - group * 8);
    int prow = group * 8 + rem % rowspan;
    int pcol = rem / rowspan;
    int row0 = prow * BM, col0 = pcol * BN;

    f32x4 acc[8][4];
    #pragma unroll
    for (int i = 0; i < 8; ++i)
        #pragma unroll
        for (int j = 0; j < 4; ++j) acc[i][j] = (f32x4){0.f,0.f,0.f,0.f};

    // one 16B staging load; i in 0..3 = {A half0, A half1, B half0, B half1}
    auto stage_part = [&](int t, int i) {
        uchar_t* Ab = smem + (t % 3) * TILE;
        uchar_t* Bb = Ab + BM*BK;
        int slot = (i & 1)*512 + tid;     // slot = r*4 + c, 1024 slots per matrix
        int r = slot >> 2, c = slot & 3;
        int sc = c ^ ((r >> 1) & 3);
        int k0 = t * BK;
        if (i < 2) gl2lds16(xn  + (size_t)(row0 + r)*EMBED + k0 + sc*16, &Ab[slot*16]);
        else       gl2lds16(x2n + (size_t)(col0 + r)*EMBED + k0 + sc*16, &Bb[slot*16]);
    };

    #pragma unroll
    for (int i = 0; i < 4; ++i) stage_part(0, i);   // 4 in flight
    #pragma unroll
    for (int i = 0; i < 4; ++i) stage_part(1, i);   // 8 in flight

    #pragma unroll
    for (int kt = 0; kt < NKT; ++kt) {
        // counted wait: stage(kt) complete; newest 4 (next tile) stay in flight
        if (kt == NKT-1) asm volatile("s_waitcnt vmcnt(0)" ::: "memory");
        else             asm volatile("s_waitcnt vmcnt(4)" ::: "memory");
        __builtin_amdgcn_s_barrier();         // buf(kt%3) globally ready

        const uchar_t* A = smem + (kt % 3) * TILE;
        const uchar_t* B = A + BM*BK;
        #pragma unroll
        for (int s = 0; s < 2; ++s) {         // K=32 halves of the K-tile
            long bfrag[4];
            int cq = s*2 + (quad >> 1);
            int h8 = (quad & 1) * 8;
            #pragma unroll
            for (int h = 0; h < 2; ++h) {     // row-half phases: 4 phases/K-tile
                long a[4];
                #pragma unroll
                for (int t4 = 0; t4 < 4; ++t4) {
                    int ra = wr*128 + (h*4 + t4)*16 + l15;
                    a[t4] = *(const long*)&A[ra*BK + ((cq ^ ((ra >> 1) & 3)) << 4) + h8];
                }
                if (h == 0) {
                    #pragma unroll
                    for (int tj = 0; tj < 4; ++tj) {
                        int rb = wc*64 + tj*16 + l15;
                        bfrag[tj] = *(const long*)&B[rb*BK + ((cq ^ ((rb >> 1) & 3)) << 4) + h8];
                    }
                }
                // one prefetch load per phase into the (dead) third buffer
                if (kt + 2 < NKT) stage_part(kt + 2, s*2 + h);
                __builtin_amdgcn_s_barrier(); // align phases across waves
                __builtin_amdgcn_s_setprio(1);
                #pragma unroll
                for (int t4 = 0; t4 < 4; ++t4)
                    #pragma unroll
                    for (int tj = 0; tj < 4; ++tj)
                        acc[h*4+t4][tj] = __builtin_amdgcn_mfma_f32_16x16x32_fp8_fp8(
                            a[t4], bfrag[tj], acc[h*4+t4][tj], 0, 0, 0);
                __builtin_amdgcn_s_setprio(0);
                __builtin_amdgcn_s_barrier();
            }
        }
    }
    __syncthreads();                          // full drain once, before smem reuse

    // ---- fused single-pass epilogue (verified r7) ----
    float* rsum_s = (float*)smem;             // [4][BM]  indexed by wc
    float* csum_s = rsum_s + 4*BM;            // [2][BN]  indexed by wr

    bool edge = (prow == nb-1) || (pcol == nb-1);
    float csv[4] = {0.f, 0.f, 0.f, 0.f};

    if (!edge) {
        // interior: gi==gj solutions: l15==quad*4+r, wr*8+ti == wc*4+tj
        //  =>  wr==wc>>1, ti==(wc&1)*4+tj.
        bool diagb = (prow == pcol) && (wr == (wc >> 1));
        #pragma unroll
        for (int ti = 0; ti < 8; ++ti) {
            #pragma unroll
            for (int r = 0; r < 4; ++r) {
                float rs = 0.f;
                #pragma unroll
                for (int tj = 0; tj < 4; ++tj) {
                    float e = __expf(acc[ti][tj][r]);
                    rs += e;
                    csv[tj] += e;
                    if (diagb && ti == (wc & 1)*4 + tj && l15 == quad*4 + r)
                        pos[row0 + wr*128 + ti*16 + quad*4 + r] = e;
                }
                rs = dpp16_red_add(rs);
                if (l15 == 0) rsum_s[wc*BM + wr*128 + ti*16 + quad*4 + r] = rs;
            }
        }
    } else {
        #pragma unroll
        for (int ti = 0; ti < 8; ++ti) {
            #pragma unroll
            for (int r = 0; r < 4; ++r) {
                int gi = row0 + wr*128 + ti*16 + quad*4 + r;
                float rs = 0.f;
                #pragma unroll
                for (int tj = 0; tj < 4; ++tj) {
                    int gj = col0 + wc*64 + tj*16 + l15;
                    float e = 0.f;
                    if (gi < N && gj < N) {
                        e = __expf(acc[ti][tj][r]);
                        if (gi == gj) pos[gi] = e;
                    }
                    rs += e;
                    csv[tj] += e;
                }
                rs = dpp16_red_add(rs);
                if (l15 == 0) rsum_s[wc*BM + wr*128 + ti*16 + quad*4 + r] = rs;
            }
        }
    }
    #pragma unroll
    for (int tj = 0; tj < 4; ++tj) {
        float cs = csv[tj];
        cs += __shfl_xor(cs, 16, 64);
        cs += __shfl_xor(cs, 32, 64);
        if (lane < 16) csum_s[wr*BN + wc*64 + tj*16 + lane] = cs;
    }
    __syncthreads();
    if (tid < BM) {
        rowpart[(size_t)pcol*Npad + row0 + tid] =
            rsum_s[tid] + rsum_s[BM + tid] + rsum_s[2*BM + tid] + rsum_s[3*BM + tid];
        colpart[(size_t)prow*Npad + col0 + tid] = csum_s[tid] + csum_s[BN + tid];
    }
}

// ---------------- Kernel 3: log-reduction + ticket finalize -----------------
__global__ __launch_bounds__(256) void k_final(
    const float* __restrict__ rowpart, const float* __restrict__ colpart,
    const float* __restrict__ pos, const float* __restrict__ partials,
    float* __restrict__ acc3, int* __restrict__ ticket,
    float* __restrict__ out, int N, int Npad, int nb, int nparts, int M)
{
    __shared__ float red1[256], red2[256], red3[256];
    int t = threadIdx.x;
    int g = blockIdx.x * 256 + t;
    int stride = gridDim.x * 256;
    float l1 = 0.f, l2 = 0.f, mo = 0.f;
    for (int i = g; i < N; i += stride) {
        float rs = 0.f, cs = 0.f;
        for (int p = 0; p < nb; ++p) {
            rs += rowpart[(size_t)p*Npad + i];    // coalesced across threads
            cs += colpart[(size_t)p*Npad + i];
        }
        float pv = pos[i];
        l1 += __logf((cs - pv) / pv);
        l2 += __logf((rs - pv) / pv);
    }
    for (int i = g; i < nparts; i += stride) mo += partials[i];
    red1[t] = l1; red2[t] = l2; red3[t] = mo; __syncthreads();
    for (int s = 128; s > 0; s >>= 1) {
        if (t < s) { red1[t] += red1[t+s]; red2[t] += red2[t+s]; red3[t] += red3[t+s]; }
        __syncthreads();
    }
    if (t == 0) {
        atomicAdd(&acc3[0], red1[0]);
        atomicAdd(&acc3[1], red2[0]);
        atomicAdd(&acc3[2], red3[0]);
        __threadfence();                          // adds visible before ticket
        int old = atomicAdd(ticket, 1);
        if (old == (int)gridDim.x - 1) {
            float a0 = atomicAdd(&acc3[0], 0.f);
            float a1 = atomicAdd(&acc3[1], 0.f);
            float a2 = atomicAdd(&acc3[2], 0.f);
            float cl = 0.5f * (a0 + a1) / (float)N;
            out[0] = cl - a2 / (float)M;
        }
    }
}

extern "C" void kernel_launch(void* const* d_in, const int* in_sizes, int n_in,
                              void* d_out, int out_size, void* d_ws, size_t ws_size,
                              hipStream_t stream)
{
    const float* x         = (const float*)d_in[0];
    const float* feats     = (const float*)d_in[1];
    const float* feat_free = (const float*)d_in[2];
    const float* ks        = (const float*)d_in[3];
    const float* Ws        = (const float*)d_in[4];
    const float* bias      = (const float*)d_in[5];
    const float* W_free    = (const float*)d_in[6];
    const float* b_free    = (const float*)d_in[7];
    const float* W1        = (const float*)d_in[8];
    const float* b1        = (const float*)d_in[9];
    const float* W2        = (const float*)d_in[10];
    const float* b2        = (const float*)d_in[11];
    const int*   motif     = (const int*)d_in[12];
    const int*   neg_uv    = (const int*)d_in[13];
    int N = in_sizes[0] / EMBED;          // 10000
    int M = in_sizes[13] / 2;             // 50000
    int nb = (N + BM - 1) / BM;           // 40
    int Npad = nb * BM;                   // 10240

    uchar_t* xnf8  = (uchar_t*)d_ws;                       // Npad*256 fp8
    uchar_t* x2nf8 = xnf8 + (size_t)Npad*EMBED;            // Npad*256 fp8
    uchar_t* H8    = x2nf8 + (size_t)Npad*EMBED;           // 12*N*64 fp8
    float* posv   = (float*)(H8 + (size_t)12*N*64);        // N
    float* acc3   = posv + N;                              // 3 + ticket
    int*   ticket = (int*)(acc3 + 3);
    float* partials = acc3 + 4;                            // MOTIF_BLOCKS
    float* rowpart  = partials + MOTIF_BLOCKS;             // nb*Npad
    float* colpart  = rowpart + (size_t)nb*Npad;           // nb*Npad

    k_pre<<<NE + NMLP, 256, 0, stream>>>(x, feats, feat_free, ks, Ws, bias,
                                         W_free, b_free, W1, b1,
                                         xnf8, x2nf8, H8, acc3, N, Npad);
    k_fused<<<MOTIF_BLOCKS + nb*nb, 512, 0, stream>>>(xnf8, x2nf8, H8, motif, neg_uv,
                                                      W2, b2, rowpart, colpart, posv,
                                                      partials, N, Npad, nb, M);
    k_final<<<256, 256, 0, stream>>>(rowpart, colpart, posv, partials, acc3, ticket,
                                     (float*)d_out, N, Npad, nb, MOTIF_BLOCKS, M);
}

// Round 9
// 238.562 us; speedup vs baseline: 2.9123x; 1.0550x over previous
//
#include <hip/hip_runtime.h>
#include <hip/hip_bf16.h>
#include <math.h>

#define EMBED 256
#define NF 3
#define DD 64
#define BM 128
#define BN 128
#define MOTIF_BLOCKS 2048
#define NE 512             // embed-role blocks in k_pre
#define NMLP 1024          // mlp-role blocks in k_pre

typedef unsigned short ushort_t;
typedef unsigned char uchar_t;
typedef float f32x4 __attribute__((ext_vector_type(4)));
typedef float f32x2 __attribute__((ext_vector_type(2)));

__device__ __forceinline__ void gl2lds16(const void* g, void* l) {
    __builtin_amdgcn_global_load_lds(
        (const __attribute__((address_space(1))) unsigned int*)g,
        (__attribute__((address_space(3))) unsigned int*)l, 16, 0, 0);
}

__device__ __forceinline__ uchar_t f2fp8(float f) {
    int p = __builtin_amdgcn_cvt_pk_fp8_f32(f, f, 0, false);  // e4m3 OCP on gfx950
    return (uchar_t)(p & 0xff);
}
template<bool HI>
__device__ __forceinline__ f32x2 pk2(unsigned int w) {
    return __builtin_amdgcn_cvt_pk_f32_fp8((int)w, HI);       // .x = low byte
}

// Sum over each contiguous 16-lane row, entirely on the VALU pipe (DPP).
__device__ __forceinline__ float dpp16_red_add(float x) {
    int v;
    v = __builtin_amdgcn_update_dpp(0, __float_as_int(x), 0xB1, 0xF, 0xF, true);  // quad_perm xor1
    x += __int_as_float(v);
    v = __builtin_amdgcn_update_dpp(0, __float_as_int(x), 0x4E, 0xF, 0xF, true);  // quad_perm xor2
    x += __int_as_float(v);
    v = __builtin_amdgcn_update_dpp(0, __float_as_int(x), 0x141, 0xF, 0xF, true); // row_half_mirror
    x += __int_as_float(v);
    v = __builtin_amdgcn_update_dpp(0, __float_as_int(x), 0x140, 0xF, 0xF, true); // row_mirror
    x += __int_as_float(v);
    return x;
}

// ---------------- Kernel 1: EMBED role + MLP role in one launch (unchanged) -
__global__ __launch_bounds__(256) void k_pre(
    const float* __restrict__ x,
    const float* __restrict__ feats,
    const float* __restrict__ feat_free,
    const float* __restrict__ ks,
    const float* __restrict__ Ws,
    const float* __restrict__ bias,
    const float* __restrict__ W_free,
    const float* __restrict__ b_free,
    const float* __restrict__ W1,     // [96][64]
    const float* __restrict__ b1,     // [64]
    uchar_t* __restrict__ xnf8,       // [Npad][256] fp8 (normalized x, PRE-SCALED by 5)
    uchar_t* __restrict__ x2nf8,      // [Npad][256] fp8 (normalized x2)
    uchar_t* __restrict__ H8,         // [4][3][N][64] fp8
    float* __restrict__ acc3,         // 3 floats + ticket to zero
    int N, int Npad)
{
    int tid = threadIdx.x;

    if (blockIdx.x >= NE) {
        // ---------------- MLP role ----------------
        int lane = tid & 63;
        int gw = ((blockIdx.x - NE) * 256 + tid) >> 6;
        int nwaves = (NMLP * 256) >> 6;

        float wcol[96];
        #pragma unroll
        for (int c = 0; c < 96; ++c) wcol[c] = W1[c*64 + lane];
        float b1l = b1[lane];
        float kv0 = ks[0], kv1 = ks[1], kv2 = ks[2];

        int total = 4 * N;
        for (int unit = gw; unit < total; unit += nwaves) {
            int node = __builtin_amdgcn_readfirstlane(unit >> 2);
            int prod = __builtin_amdgcn_readfirstlane(unit & 3);
            float fc[32];
            if (prod < 3) {
                const float* P = feats + ((size_t)prod*N + node)*32;
                float red[32];
                #pragma unroll
                for (int c = 0; c < 32; ++c) { fc[c] = P[c]; red[c] = fc[c]*fc[c]; }
                // butterfly tree bit-exact vs embed role's shfl_xor chain
                #pragma unroll
                for (int st = 1; st < 32; st <<= 1)
                    #pragma unroll
                    for (int c = 0; c < 32; c += 2*st) red[c] = red[c] + red[c + st];
                float s = red[0];
                float k = (prod == 0) ? kv0 : (prod == 1) ? kv1 : kv2;
                float scale = 0.45f / (sqrtf(s) * sqrtf(fabsf(k)));
                #pragma unroll
                for (int c = 0; c < 32; ++c) fc[c] *= scale;
            } else {
                const float* P = feat_free + (size_t)node*32;
                #pragma unroll
                for (int c = 0; c < 32; ++c) fc[c] = P[c];
            }
            #pragma unroll
            for (int s = 0; s < 3; ++s) {
                float h = (s == 2) ? b1l : 0.f;
                #pragma unroll
                for (int c = 0; c < 32; ++c) h = fmaf(fc[c], wcol[s*32 + c], h);
                H8[(((size_t)prod*3 + s)*N + node)*64 + lane] = f2fp8(h);
            }
        }
        return;
    }

    // ---------------- EMBED role ----------------
    int wave = tid >> 6;
    int t    = tid & 63;
    int gtid = blockIdx.x * 256 + tid;
    int stride = NE * 256;

    for (int i = gtid; i < 4; i += stride) acc3[i] = 0.f;   // [3] = ticket
    {
        int pad = (Npad - N) * (EMBED/4);
        int* pa = (int*)(xnf8  + (size_t)N*EMBED);
        int* pb = (int*)(x2nf8 + (size_t)N*EMBED);
        for (int i = gtid; i < pad; i += stride) { pa[i] = 0; pb[i] = 0; }
    }

    __shared__ float Wl[128*65];      // rows: [i*32+c] for Ws, [96+c] for W_free
    __shared__ float xi_s[4][NF][32];
    __shared__ float ff_s[4][32];

    for (int e = tid; e < NF*DD*32; e += 256) {
        int i = e >> 11, rem = e & 2047, tr = rem >> 5, c = rem & 31;
        Wl[(i*32 + c)*65 + tr] = Ws[e];
    }
    for (int e = tid; e < DD*32; e += 256) {
        int tr = e >> 5, c = e & 31;
        Wl[(96 + c)*65 + tr] = W_free[e];
    }
    __syncthreads();                   // Wl ready; no barriers needed below

    float (*xi)[32] = xi_s[wave];
    float* ffs = ff_s[wave];
    int ngroups = (N + 3) >> 2;

    for (int grp = blockIdx.x; grp < ngroups; grp += NE) {
        int n = grp*4 + wave;
        if (n >= N) continue;          // wave-uniform

        float v[NF];
        float ffv = 0.f;
        if (t < 32) {
            #pragma unroll
            for (int i = 0; i < NF; ++i) v[i] = feats[((size_t)i*N + n)*32 + t];
            ffv = feat_free[(size_t)n*32 + t];
        } else {
            #pragma unroll
            for (int i = 0; i < NF; ++i) v[i] = 0.f;
        }

        float num[NF];
        #pragma unroll
        for (int i = 0; i < NF; ++i) {
            float s = v[i]*v[i];
            s += __shfl_xor(s, 1, 64);  s += __shfl_xor(s, 2, 64);
            s += __shfl_xor(s, 4, 64);  s += __shfl_xor(s, 8, 64);
            s += __shfl_xor(s, 16, 64);
            s = __shfl(s, 0, 64);
            float k = ks[i];
            float scale = 0.45f / (sqrtf(s) * sqrtf(fabsf(k)));
            float xv = v[i] * scale;
            if (t < 32) xi[i][t] = xv;             // wave-local LDS (lgkmcnt ordering)
            num[i] = 1.0f + k * (scale*scale*s);
        }
        if (t < 32) ffs[t] = ffv;

        float z[4];
        float zsq = 0.f;
        #pragma unroll
        for (int i = 0; i < NF; ++i) {
            float div = 0.f;
            #pragma unroll
            for (int c = 0; c < 32; ++c) {
                float d = xi[i][c] - Wl[(i*32 + c)*65 + t];
                div += d*d;
            }
            float dist = __logf(num[i] / (div + 1e-5f));
            float zz = __expf(15.5f * dist) * __cosf(dist + bias[i*DD + t]);
            z[i] = zz;
            zsq += zz*zz;
        }
        {
            float dot = 0.f;
            #pragma unroll
            for (int c = 0; c < 32; ++c) dot = fmaf(ffs[c], Wl[(96 + c)*65 + t], dot);
            float zz = __expf(15.5f * dot) * __cosf(dot + b_free[t]);
            z[3] = zz;
            zsq += zz*zz;
        }
        zsq += __shfl_xor(zsq, 1, 64);  zsq += __shfl_xor(zsq, 2, 64);
        zsq += __shfl_xor(zsq, 4, 64);  zsq += __shfl_xor(zsq, 8, 64);
        zsq += __shfl_xor(zsq, 16, 64); zsq += __shfl_xor(zsq, 32, 64);
        float iv2 = 1.0f / sqrtf(zsq);

        #pragma unroll
        for (int i = 0; i < NF; ++i) x2nf8[(size_t)n*EMBED + i*DD + t] = f2fp8(z[i]*iv2);
        x2nf8[(size_t)n*EMBED + 192 + t] = f2fp8(z[3]*iv2);

        float xv[4];
        float s1 = 0.f;
        #pragma unroll
        for (int q = 0; q < 4; ++q) { xv[q] = x[(size_t)n*EMBED + q*64 + t]; s1 += xv[q]*xv[q]; }
        s1 += __shfl_xor(s1, 1, 64);  s1 += __shfl_xor(s1, 2, 64);
        s1 += __shfl_xor(s1, 4, 64);  s1 += __shfl_xor(s1, 8, 64);
        s1 += __shfl_xor(s1, 16, 64); s1 += __shfl_xor(s1, 32, 64);
        float iv1 = 5.0f / sqrtf(s1);          // pre-scale by 5 (1/TEMP)
        #pragma unroll
        for (int q = 0; q < 4; ++q) xnf8[(size_t)n*EMBED + q*64 + t] = f2fp8(xv[q]*iv1);
    }
}

// ---------------- Kernel 2: FUSED motif + single-stage 128^2 GEMM -----------
// Round 9. K=256 fits entirely in LDS for a 128^2 tile (64KB A+B), so stage
// ONCE (16 gl2lds16/thread), ONE barrier, then 8 uninterrupted K-steps
// (128 MFMA/wave) with ds_reads compiler-scheduled across the whole loop —
// r8 showed deep phase-pipelines are the wrong regime at NKT=4 (no steady
// state; 1 block/CU exposed every stall). 64KB -> 2 blocks/CU provide the
// cross-block overlap (m114) that hides staging+epilogue. Swizzle for 256B
// rows: chunk sc = c ^ (r&15) -> read lanes land 2/bank (free, m136);
// staging keeps linear LDS dest + permuted global source (rule #21).
__global__ __launch_bounds__(256, 4) void k_fused(
    const uchar_t* __restrict__ xn, const uchar_t* __restrict__ x2n,
    const uchar_t* __restrict__ H,        // [4][3][N][64] fp8
    const int* __restrict__ motif,        // [3][M]
    const int* __restrict__ neg_uv,       // [2][M]
    const float* __restrict__ W2,
    const float* __restrict__ b2,
    float* __restrict__ rowpart,          // [nb][Npad]  (pcol-indexed partials)
    float* __restrict__ colpart,          // [nb][Npad]  (prow-indexed partials)
    float* __restrict__ pos,
    float* __restrict__ partials,         // [MOTIF_BLOCKS]
    int N, int Npad, int nb, int M)
{
    __shared__ __align__(16) uchar_t smem[BM*EMBED + BN*EMBED];   // 65536B

    if (blockIdx.x < MOTIF_BLOCKS) {
        // ---------------- motif path (r6-verified, 256 threads) ----------
        float* wred = (float*)smem;
        int lane = threadIdx.x & 63;
        int sub  = lane >> 3;
        int ch   = (lane & 7) * 8;
        int caseId = blockIdx.x & 7;
        int rank   = (blockIdx.x >> 3) * 4 + (threadIdx.x >> 6);   // 0..1023
        int prod  = caseId >> 1;
        int isneg = caseId & 1;
        const uchar_t* Hu = H + ((size_t)prod*3 + 0)*N*64;
        const uchar_t* Hv = H + ((size_t)prod*3 + 1)*N*64;
        const uchar_t* Hw = H + ((size_t)prod*3 + 2)*N*64;
        const int* iu = isneg ? neg_uv       : motif;
        const int* iv = isneg ? (neg_uv + M) : (motif + M);
        const int* iw = motif + 2*M;

        float w2c[8];
        #pragma unroll
        for (int c = 0; c < 8; ++c) w2c[c] = W2[ch + c];
        float b2v = b2[0];

        float accl = 0.f;
        #pragma unroll 2
        for (int r0 = rank*8; r0 < M; r0 += 8192) {
            int r = r0 + sub;
            bool ok = (r < M);
            int rc = ok ? r : 0;
            int u = iu[rc], v = iv[rc], w = iw[rc];
            uint2 du = *(const uint2*)&Hu[(size_t)u*64 + ch];
            uint2 dv = *(const uint2*)&Hv[(size_t)v*64 + ch];
            uint2 dw = *(const uint2*)&Hw[(size_t)w*64 + ch];
            float pl = 0.f;
            {
                f32x2 s;
                s = pk2<false>(du.x) + pk2<false>(dv.x) + pk2<false>(dw.x);
                pl = fmaf(fmaxf(s.x,0.f), w2c[0], pl);  pl = fmaf(fmaxf(s.y,0.f), w2c[1], pl);
                s = pk2<true>(du.x) + pk2<true>(dv.x) + pk2<true>(dw.x);
                pl = fmaf(fmaxf(s.x,0.f), w2c[2], pl);  pl = fmaf(fmaxf(s.y,0.f), w2c[3], pl);
                s = pk2<false>(du.y) + pk2<false>(dv.y) + pk2<false>(dw.y);
                pl = fmaf(fmaxf(s.x,0.f), w2c[4], pl);  pl = fmaf(fmaxf(s.y,0.f), w2c[5], pl);
                s = pk2<true>(du.y) + pk2<true>(dv.y) + pk2<true>(dw.y);
                pl = fmaf(fmaxf(s.x,0.f), w2c[6], pl);  pl = fmaf(fmaxf(s.y,0.f), w2c[7], pl);
            }
            pl += __shfl_xor(pl, 1, 64);
            pl += __shfl_xor(pl, 2, 64);
            pl += __shfl_xor(pl, 4, 64);
            float logit = pl + b2v;
            float z = isneg ? -logit : logit;
            float sp = fmaxf(-z, 0.f) + __logf(1.f + __expf(-fabsf(z)));
            accl -= ok ? sp : 0.f;
        }
        #pragma unroll
        for (int m = 1; m < 64; m <<= 1) accl += __shfl_xor(accl, m, 64);

        if (lane == 0) wred[threadIdx.x >> 6] = accl;
        __syncthreads();
        if (threadIdx.x == 0)
            partials[blockIdx.x] = (wred[0] + wred[1] + wred[2] + wred[3]) * 0.125f;
        return;
    }

    // ---------------- sim path ----------------
    uchar_t* As = smem;
    uchar_t* Bs = smem + BM*EMBED;

    int tid  = threadIdx.x;
    int lane = tid & 63;
    int w    = tid >> 6;
    int wr   = w >> 1, wc = w & 1;
    int quad = lane >> 4, l15 = lane & 15;

    int pid = blockIdx.x - MOTIF_BLOCKS;
    // bijective XCD swizzle (m204)
    int nwg = nb * nb;
    int qq = nwg >> 3, rr = nwg & 7;
    int xcd = pid & 7, idx = pid >> 3;
    int wg = (xcd < rr ? xcd*(qq+1) : rr*(qq+1) + (xcd-rr)*qq) + idx;

    int per_group = 8 * nb;
    int group = wg / per_group;
    int rem = wg - group * per_group;
    int rowspan = min(8, nb - group * 8);
    int prow = group * 8 + rem % rowspan;
    int pcol = rem / rowspan;
    int row0 = prow * BM, col0 = pcol * BN;

    // single-shot staging of the WHOLE K: 2048 slots per matrix, 16B each
    #pragma unroll
    for (int i = 0; i < 8; ++i) {
        int slot = i*256 + tid;           // slot = r*16 + c, c = 16B chunk 0..15
        int r = slot >> 4, c = slot & 15;
        int sc = c ^ (r & 15);            // involution: LDS[r][c] = G[r][c^(r&15)]
        gl2lds16(xn  + (size_t)(row0 + r)*EMBED + sc*16, &As[slot*16]);
        gl2lds16(x2n + (size_t)(col0 + r)*EMBED + sc*16, &Bs[slot*16]);
    }
    __syncthreads();                      // vmcnt(0) drain + barrier (the ONLY one)

    f32x4 acc[4][4];
    #pragma unroll
    for (int i = 0; i < 4; ++i)
        #pragma unroll
        for (int j = 0; j < 4; ++j) acc[i][j] = (f32x4){0.f,0.f,0.f,0.f};

    #pragma unroll
    for (int s = 0; s < 8; ++s) {         // 8 k-steps of K=32, no barriers
        long a[4], b[4];
        int cq = s*2 + (quad >> 1);       // global 16B chunk 0..15
        int h8 = (quad & 1) * 8;
        #pragma unroll
        for (int ti = 0; ti < 4; ++ti) {
            int ra = wr*64 + ti*16 + l15;
            a[ti] = *(const long*)&As[ra*EMBED + ((cq ^ (ra & 15)) << 4) + h8];
        }
        #pragma unroll
        for (int tj = 0; tj < 4; ++tj) {
            int rb = wc*64 + tj*16 + l15;
            b[tj] = *(const long*)&Bs[rb*EMBED + ((cq ^ (rb & 15)) << 4) + h8];
        }
        __builtin_amdgcn_s_setprio(1);
        #pragma unroll
        for (int ti = 0; ti < 4; ++ti)
            #pragma unroll
            for (int tj = 0; tj < 4; ++tj)
                acc[ti][tj] = __builtin_amdgcn_mfma_f32_16x16x32_fp8_fp8(a[ti], b[tj], acc[ti][tj], 0, 0, 0);
        __builtin_amdgcn_s_setprio(0);
    }
    __syncthreads();                      // all ds_reads done; smem reusable

    // ---- fused single-pass epilogue (r4/r6-verified) ----
    float* rsum_s = (float*)smem;         // [2][BM]  indexed by wc
    float* csum_s = rsum_s + 2*BM;        // [2][BM]  indexed by wr

    bool edge = (prow == nb-1) || (pcol == nb-1);
    float csv[4] = {0.f, 0.f, 0.f, 0.f};

    if (!edge) {
        bool diagb = (prow == pcol) && (wr == wc);
        #pragma unroll
        for (int ti = 0; ti < 4; ++ti) {
            #pragma unroll
            for (int r = 0; r < 4; ++r) {
                float rs = 0.f;
                #pragma unroll
                for (int tj = 0; tj < 4; ++tj) {
                    float e = __expf(acc[ti][tj][r]);
                    rs += e;
                    csv[tj] += e;
                    if (tj == ti && diagb && l15 == quad*4 + r)
                        pos[row0 + wr*64 + ti*16 + quad*4 + r] = e;
                }
                rs = dpp16_red_add(rs);
                if (l15 == 0) rsum_s[wc*BM + wr*64 + ti*16 + quad*4 + r] = rs;
            }
        }
    } else {
        #pragma unroll
        for (int ti = 0; ti < 4; ++ti) {
            #pragma unroll
            for (int r = 0; r < 4; ++r) {
                int gi = row0 + wr*64 + ti*16 + quad*4 + r;
                float rs = 0.f;
                #pragma unroll
                for (int tj = 0; tj < 4; ++tj) {
                    int gj = col0 + wc*64 + tj*16 + l15;
                    float e = 0.f;
                    if (gi < N && gj < N) {
                        e = __expf(acc[ti][tj][r]);
                        if (gi == gj) pos[gi] = e;
                    }
                    rs += e;
                    csv[tj] += e;
                }
                rs = dpp16_red_add(rs);
                if (l15 == 0) rsum_s[wc*BM + wr*64 + ti*16 + quad*4 + r] = rs;
            }
        }
    }
    #pragma unroll
    for (int tj = 0; tj < 4; ++tj) {
        float cs = csv[tj];
        cs += __shfl_xor(cs, 16, 64);
        cs += __shfl_xor(cs, 32, 64);
        if (lane < 16) csum_s[wr*BM + wc*64 + tj*16 + lane] = cs;
    }
    __syncthreads();
    if (tid < BM) {
        rowpart[(size_t)pcol*Npad + row0 + tid] = rsum_s[tid] + rsum_s[BM + tid];
        colpart[(size_t)prow*Npad + col0 + tid] = csum_s[tid] + csum_s[BM + tid];
    }
}

// ---------------- Kernel 3: log-reduction + ticket finalize -----------------
__global__ __launch_bounds__(256) void k_final(
    const float* __restrict__ rowpart, const float* __restrict__ colpart,
    const float* __restrict__ pos, const float* __restrict__ partials,
    float* __restrict__ acc3, int* __restrict__ ticket,
    float* __restrict__ out, int N, int Npad, int nb, int nparts, int M)
{
    __shared__ float red1[256], red2[256], red3[256];
    int t = threadIdx.x;
    int g = blockIdx.x * 256 + t;
    int stride = gridDim.x * 256;
    float l1 = 0.f, l2 = 0.f, mo = 0.f;
    for (int i = g; i < N; i += stride) {
        float rs = 0.f, cs = 0.f;
        for (int p = 0; p < nb; ++p) {
            rs += rowpart[(size_t)p*Npad + i];    // coalesced across threads
            cs += colpart[(size_t)p*Npad + i];
        }
        float pv = pos[i];
        l1 += __logf((cs - pv) / pv);
        l2 += __logf((rs - pv) / pv);
    }
    for (int i = g; i < nparts; i += stride) mo += partials[i];
    red1[t] = l1; red2[t] = l2; red3[t] = mo; __syncthreads();
    for (int s = 128; s > 0; s >>= 1) {
        if (t < s) { red1[t] += red1[t+s]; red2[t] += red2[t+s]; red3[t] += red3[t+s]; }
        __syncthreads();
    }
    if (t == 0) {
        atomicAdd(&acc3[0], red1[0]);
        atomicAdd(&acc3[1], red2[0]);
        atomicAdd(&acc3[2], red3[0]);
        __threadfence();                          // adds visible before ticket
        int old = atomicAdd(ticket, 1);
        if (old == (int)gridDim.x - 1) {
            float a0 = atomicAdd(&acc3[0], 0.f);
            float a1 = atomicAdd(&acc3[1], 0.f);
            float a2 = atomicAdd(&acc3[2], 0.f);
            float cl = 0.5f * (a0 + a1) / (float)N;
            out[0] = cl - a2 / (float)M;
        }
    }
}

extern "C" void kernel_launch(void* const* d_in, const int* in_sizes, int n_in,
                              void* d_out, int out_size, void* d_ws, size_t ws_size,
                              hipStream_t stream)
{
    const float* x         = (const float*)d_in[0];
    const float* feats     = (const float*)d_in[1];
    const float* feat_free = (const float*)d_in[2];
    const float* ks        = (const float*)d_in[3];
    const float* Ws        = (const float*)d_in[4];
    const float* bias      = (const float*)d_in[5];
    const float* W_free    = (const float*)d_in[6];
    const float* b_free    = (const float*)d_in[7];
    const float* W1        = (const float*)d_in[8];
    const float* b1        = (const float*)d_in[9];
    const float* W2        = (const float*)d_in[10];
    const float* b2        = (const float*)d_in[11];
    const int*   motif     = (const int*)d_in[12];
    const int*   neg_uv    = (const int*)d_in[13];
    int N = in_sizes[0] / EMBED;          // 10000
    int M = in_sizes[13] / 2;             // 50000
    int nb = (N + BM - 1) / BM;           // 79
    int Npad = nb * BM;                   // 10112

    uchar_t* xnf8  = (uchar_t*)d_ws;                       // Npad*256 fp8
    uchar_t* x2nf8 = xnf8 + (size_t)Npad*EMBED;            // Npad*256 fp8
    uchar_t* H8    = x2nf8 + (size_t)Npad*EMBED;           // 12*N*64 fp8
    float* posv   = (float*)(H8 + (size_t)12*N*64);        // N
    float* acc3   = posv + N;                              // 3 + ticket
    int*   ticket = (int*)(acc3 + 3);
    float* partials = acc3 + 4;                            // MOTIF_BLOCKS
    float* rowpart  = partials + MOTIF_BLOCKS;             // nb*Npad
    float* colpart  = rowpart + (size_t)nb*Npad;           // nb*Npad

    k_pre<<<NE + NMLP, 256, 0, stream>>>(x, feats, feat_free, ks, Ws, bias,
                                         W_free, b_free, W1, b1,
                                         xnf8, x2nf8, H8, acc3, N, Npad);
    k_fused<<<MOTIF_BLOCKS + nb*nb, 256, 0, stream>>>(xnf8, x2nf8, H8, motif, neg_uv,
                                                      W2, b2, rowpart, colpart, posv,
                                                      partials, N, Npad, nb, M);
    k_final<<<256, 256, 0, stream>>>(rowpart, colpart, posv, partials, acc3, ticket,
                                     (float*)d_out, N, Npad, nb, MOTIF_BLOCKS, M);
}

// Round 10
// 219.697 us; speedup vs baseline: 3.1623x; 1.0859x over previous
//
#include <hip/hip_runtime.h>
#include <hip/hip_bf16.h>
#include <math.h>

#define EMBED 256
#define NF 3
#define DD 64
#define BM 128
#define BN 128
#define BK 64              // fp8 K-elements per pipeline phase
#define NKT 4              // EMBED / BK
#define MOTIF_BLOCKS 2048

typedef unsigned short ushort_t;
typedef unsigned char uchar_t;
typedef float f32x4 __attribute__((ext_vector_type(4)));
typedef float f32x2 __attribute__((ext_vector_type(2)));

__device__ __forceinline__ void gl2lds16(const void* g, void* l) {
    __builtin_amdgcn_global_load_lds(
        (const __attribute__((address_space(1))) unsigned int*)g,
        (__attribute__((address_space(3))) unsigned int*)l, 16, 0, 0);
}

__device__ __forceinline__ uchar_t f2fp8(float f) {
    int p = __builtin_amdgcn_cvt_pk_fp8_f32(f, f, 0, false);  // e4m3 OCP on gfx950
    return (uchar_t)(p & 0xff);
}
template<bool HI>
__device__ __forceinline__ f32x2 pk2(unsigned int w) {
    return __builtin_amdgcn_cvt_pk_f32_fp8((int)w, HI);       // .x = low byte
}

// Sum over the 16 lanes of each contiguous 16-lane row, entirely on the VALU
// pipe (DPP). After 4 steps every lane holds its 16-group total.
__device__ __forceinline__ float dpp16_red_add(float x) {
    int v;
    v = __builtin_amdgcn_update_dpp(0, __float_as_int(x), 0xB1, 0xF, 0xF, true);  // quad_perm xor1
    x += __int_as_float(v);
    v = __builtin_amdgcn_update_dpp(0, __float_as_int(x), 0x4E, 0xF, 0xF, true);  // quad_perm xor2
    x += __int_as_float(v);
    v = __builtin_amdgcn_update_dpp(0, __float_as_int(x), 0x141, 0xF, 0xF, true); // row_half_mirror
    x += __int_as_float(v);
    v = __builtin_amdgcn_update_dpp(0, __float_as_int(x), 0x140, 0xF, 0xF, true); // row_mirror
    x += __int_as_float(v);
    return x;
}

// ---------------- Kernel 1: normalize + random_mapping (r4-exact) -----------
__global__ __launch_bounds__(256) void k_embed(
    const float* __restrict__ x,
    const float* __restrict__ feats,
    const float* __restrict__ feat_free,
    const float* __restrict__ ks,
    const float* __restrict__ Ws,
    const float* __restrict__ bias,
    const float* __restrict__ W_free,
    const float* __restrict__ b_free,
    float* __restrict__ p_out,        // [3][N][32]
    uchar_t* __restrict__ xnf8,       // [Npad][256] fp8 (normalized x, PRE-SCALED by 5)
    uchar_t* __restrict__ x2nf8,      // [Npad][256] fp8 (normalized x2)
    float* __restrict__ acc3,         // 3 floats + ticket to zero
    int N, int Npad)
{
    int tid  = threadIdx.x;
    int wave = tid >> 6;
    int t    = tid & 63;
    int gtid = blockIdx.x * 256 + tid;
    int stride = gridDim.x * 256;

    for (int i = gtid; i < 4; i += stride) acc3[i] = 0.f;   // [3] = ticket
    {
        int pad = (Npad - N) * (EMBED/4);
        int* pa = (int*)(xnf8  + (size_t)N*EMBED);
        int* pb = (int*)(x2nf8 + (size_t)N*EMBED);
        for (int i = gtid; i < pad; i += stride) { pa[i] = 0; pb[i] = 0; }
    }

    __shared__ float Wl[128*65];      // rows: [i*32+c] for Ws, [96+c] for W_free
    __shared__ float xi_s[4][NF][32];
    __shared__ float ff_s[4][32];

    for (int e = tid; e < NF*DD*32; e += 256) {
        int i = e >> 11, rem = e & 2047, tr = rem >> 5, c = rem & 31;
        Wl[(i*32 + c)*65 + tr] = Ws[e];
    }
    for (int e = tid; e < DD*32; e += 256) {
        int tr = e >> 5, c = e & 31;
        Wl[(96 + c)*65 + tr] = W_free[e];
    }
    __syncthreads();                   // Wl ready; no barriers needed below

    float (*xi)[32] = xi_s[wave];
    float* ffs = ff_s[wave];
    int ngroups = (N + 3) >> 2;

    for (int grp = blockIdx.x; grp < ngroups; grp += gridDim.x) {
        int n = grp*4 + wave;
        if (n >= N) continue;          // wave-uniform

        float v[NF];
        float ffv = 0.f;
        if (t < 32) {
            #pragma unroll
            for (int i = 0; i < NF; ++i) v[i] = feats[((size_t)i*N + n)*32 + t];
            ffv = feat_free[(size_t)n*32 + t];
        } else {
            #pragma unroll
            for (int i = 0; i < NF; ++i) v[i] = 0.f;
        }

        float num[NF];
        #pragma unroll
        for (int i = 0; i < NF; ++i) {
            float s = v[i]*v[i];
            s += __shfl_xor(s, 1, 64);  s += __shfl_xor(s, 2, 64);
            s += __shfl_xor(s, 4, 64);  s += __shfl_xor(s, 8, 64);
            s += __shfl_xor(s, 16, 64);
            s = __shfl(s, 0, 64);
            float k = ks[i];
            float scale = 0.45f / (sqrtf(s) * sqrtf(fabsf(k)));
            float xv = v[i] * scale;
            if (t < 32) {
                xi[i][t] = xv;                       // wave-local LDS (lgkmcnt ordering)
                p_out[((size_t)i*N + n)*32 + t] = xv;
            }
            num[i] = 1.0f + k * (scale*scale*s);
        }
        if (t < 32) ffs[t] = ffv;

        float z[4];
        float zsq = 0.f;
        #pragma unroll
        for (int i = 0; i < NF; ++i) {
            float div = 0.f;
            #pragma unroll
            for (int c = 0; c < 32; ++c) {
                float d = xi[i][c] - Wl[(i*32 + c)*65 + t];
                div += d*d;
            }
            float dist = __logf(num[i] / (div + 1e-5f));
            float zz = __expf(15.5f * dist) * __cosf(dist + bias[i*DD + t]);
            z[i] = zz;
            zsq += zz*zz;
        }
        {
            float dot = 0.f;
            #pragma unroll
            for (int c = 0; c < 32; ++c) dot = fmaf(ffs[c], Wl[(96 + c)*65 + t], dot);
            float zz = __expf(15.5f * dot) * __cosf(dot + b_free[t]);
            z[3] = zz;
            zsq += zz*zz;
        }
        zsq += __shfl_xor(zsq, 1, 64);  zsq += __shfl_xor(zsq, 2, 64);
        zsq += __shfl_xor(zsq, 4, 64);  zsq += __shfl_xor(zsq, 8, 64);
        zsq += __shfl_xor(zsq, 16, 64); zsq += __shfl_xor(zsq, 32, 64);
        float iv2 = 1.0f / sqrtf(zsq);

        #pragma unroll
        for (int i = 0; i < NF; ++i) x2nf8[(size_t)n*EMBED + i*DD + t] = f2fp8(z[i]*iv2);
        x2nf8[(size_t)n*EMBED + 192 + t] = f2fp8(z[3]*iv2);

        float xv[4];
        float s1 = 0.f;
        #pragma unroll
        for (int q = 0; q < 4; ++q) { xv[q] = x[(size_t)n*EMBED + q*64 + t]; s1 += xv[q]*xv[q]; }
        s1 += __shfl_xor(s1, 1, 64);  s1 += __shfl_xor(s1, 2, 64);
        s1 += __shfl_xor(s1, 4, 64);  s1 += __shfl_xor(s1, 8, 64);
        s1 += __shfl_xor(s1, 16, 64); s1 += __shfl_xor(s1, 32, 64);
        float iv1 = 5.0f / sqrtf(s1);          // pre-scale by 5 (1/TEMP)
        #pragma unroll
        for (int q = 0; q < 4; ++q) xnf8[(size_t)n*EMBED + q*64 + t] = f2fp8(xv[q]*iv1);
    }
}

// ---------------- Kernel 2: per-node MLP hidden partials -> fp8 H -----------
__global__ __launch_bounds__(256) void k_mlp1(
    const float* __restrict__ p,          // [3][N][32]
    const float* __restrict__ feat_free,  // [N][32]
    const float* __restrict__ W1,         // [96][64]
    const float* __restrict__ b1,         // [64]
    uchar_t* __restrict__ H,              // [4][3][N][64] fp8
    int N)
{
    int lane = threadIdx.x & 63;
    int gw = (blockIdx.x * blockDim.x + threadIdx.x) >> 6;
    int nwaves = (gridDim.x * blockDim.x) >> 6;

    float wcol[96];
    #pragma unroll
    for (int c = 0; c < 96; ++c) wcol[c] = W1[c*64 + lane];
    float b1l = b1[lane];

    int total = 4 * N;
    for (int unit = gw; unit < total; unit += nwaves) {
        int node = __builtin_amdgcn_readfirstlane(unit >> 2);
        int prod = __builtin_amdgcn_readfirstlane(unit & 3);
        const float* P = (prod < 3) ? (p + ((size_t)prod*N + node)*32)
                                    : (feat_free + (size_t)node*32);
        float fc[32];
        #pragma unroll
        for (int c = 0; c < 32; ++c) fc[c] = P[c];
        #pragma unroll
        for (int s = 0; s < 3; ++s) {
            float h = (s == 2) ? b1l : 0.f;
            #pragma unroll
            for (int c = 0; c < 32; ++c) h = fmaf(fc[c], wcol[s*32 + c], h);
            H[(((size_t)prod*3 + s)*N + node)*64 + lane] = f2fp8(h);
        }
    }
}

// ---------------- Kernel 3: FUSED sim-GEMM (first) + motif (after) ----------
// r4-exact sim path (best measured: 80.5 µs, T4 counted-vmcnt, fused DPP
// epilogue). Round 10 rider: SIM blocks occupy blockIdx [0, nb*nb) so the
// long compute-bound tiles launch first; short latency-bound motif blocks
// backfill gaps and the tail instead of front-loading every CU.
__global__ __launch_bounds__(256, 4) void k_fused(
    const uchar_t* __restrict__ xn, const uchar_t* __restrict__ x2n,
    const uchar_t* __restrict__ H,        // [4][3][N][64] fp8
    const int* __restrict__ motif,        // [3][M]
    const int* __restrict__ neg_uv,       // [2][M]
    const float* __restrict__ W2,
    const float* __restrict__ b2,
    float* __restrict__ rowpart,          // [nb][Npad]  (pcol-indexed partials)
    float* __restrict__ colpart,          // [nb][Npad]  (prow-indexed partials)
    float* __restrict__ pos,
    float* __restrict__ partials,         // [MOTIF_BLOCKS]
    int N, int Npad, int nb, int M)
{
    __shared__ __align__(16) uchar_t smem[2*(BM*BK + BN*BK)];   // 32768B

    int nwg = nb * nb;
    if (blockIdx.x >= nwg) {
        // ---------------- motif path ----------------
        float* wred = (float*)smem;
        int pidm = blockIdx.x - nwg;          // 0..MOTIF_BLOCKS-1
        int lane = threadIdx.x & 63;
        int sub  = lane >> 3;
        int ch   = (lane & 7) * 8;
        int caseId = pidm & 7;
        int rank   = (pidm >> 3) * 4 + (threadIdx.x >> 6);   // 0..1023
        int prod  = caseId >> 1;
        int isneg = caseId & 1;
        const uchar_t* Hu = H + ((size_t)prod*3 + 0)*N*64;
        const uchar_t* Hv = H + ((size_t)prod*3 + 1)*N*64;
        const uchar_t* Hw = H + ((size_t)prod*3 + 2)*N*64;
        const int* iu = isneg ? neg_uv       : motif;
        const int* iv = isneg ? (neg_uv + M) : (motif + M);
        const int* iw = motif + 2*M;

        float w2c[8];
        #pragma unroll
        for (int c = 0; c < 8; ++c) w2c[c] = W2[ch + c];
        float b2v = b2[0];

        float accl = 0.f;
        #pragma unroll 2
        for (int r0 = rank*8; r0 < M; r0 += 8192) {
            int r = r0 + sub;
            bool ok = (r < M);
            int rc = ok ? r : 0;
            int u = iu[rc], v = iv[rc], w = iw[rc];
            uint2 du = *(const uint2*)&Hu[(size_t)u*64 + ch];
            uint2 dv = *(const uint2*)&Hv[(size_t)v*64 + ch];
            uint2 dw = *(const uint2*)&Hw[(size_t)w*64 + ch];
            float pl = 0.f;
            {
                f32x2 s;
                s = pk2<false>(du.x) + pk2<false>(dv.x) + pk2<false>(dw.x);
                pl = fmaf(fmaxf(s.x,0.f), w2c[0], pl);  pl = fmaf(fmaxf(s.y,0.f), w2c[1], pl);
                s = pk2<true>(du.x) + pk2<true>(dv.x) + pk2<true>(dw.x);
                pl = fmaf(fmaxf(s.x,0.f), w2c[2], pl);  pl = fmaf(fmaxf(s.y,0.f), w2c[3], pl);
                s = pk2<false>(du.y) + pk2<false>(dv.y) + pk2<false>(dw.y);
                pl = fmaf(fmaxf(s.x,0.f), w2c[4], pl);  pl = fmaf(fmaxf(s.y,0.f), w2c[5], pl);
                s = pk2<true>(du.y) + pk2<true>(dv.y) + pk2<true>(dw.y);
                pl = fmaf(fmaxf(s.x,0.f), w2c[6], pl);  pl = fmaf(fmaxf(s.y,0.f), w2c[7], pl);
            }
            pl += __shfl_xor(pl, 1, 64);
            pl += __shfl_xor(pl, 2, 64);
            pl += __shfl_xor(pl, 4, 64);
            float logit = pl + b2v;
            float z = isneg ? -logit : logit;
            float sp = fmaxf(-z, 0.f) + __logf(1.f + __expf(-fabsf(z)));
            accl -= ok ? sp : 0.f;
        }
        #pragma unroll
        for (int m = 1; m < 64; m <<= 1) accl += __shfl_xor(accl, m, 64);

        if (lane == 0) wred[threadIdx.x >> 6] = accl;
        __syncthreads();
        if (threadIdx.x == 0)
            partials[pidm] = (wred[0] + wred[1] + wred[2] + wred[3]) * 0.125f;
        return;
    }

    // ---------------- sim path ----------------
    int tid  = threadIdx.x;
    int lane = tid & 63;
    int w    = tid >> 6;
    int wr   = w >> 1, wc = w & 1;
    int quad = lane >> 4, l15 = lane & 15;

    int pid = blockIdx.x;
    // bijective XCD swizzle (m204)
    int qq = nwg >> 3, rr = nwg & 7;
    int xcd = pid & 7, idx = pid >> 3;
    int wg = (xcd < rr ? xcd*(qq+1) : rr*(qq+1) + (xcd-rr)*qq) + idx;

    int per_group = 8 * nb;
    int group = wg / per_group;
    int rem = wg - group * per_group;
    int rowspan = min(8, nb - group * 8);
    int prow = group * 8 + rem % rowspan;
    int pcol = rem / rowspan;
    int row0 = prow * BM, col0 = pcol * BN;

    f32x4 acc[4][4];
    #pragma unroll
    for (int i = 0; i < 4; ++i)
        #pragma unroll
        for (int j = 0; j < 4; ++j) acc[i][j] = (f32x4){0.f,0.f,0.f,0.f};

    auto stage = [&](int t) {
        uchar_t* A = smem + (t & 1) * (BM*BK + BN*BK);
        uchar_t* B = A + BM*BK;
        int k0 = t * BK;
        #pragma unroll
        for (int i = 0; i < 2; ++i) {
            int slot = i*256 + tid;          // slot = r*4 + c, 512 slots per tile
            int r = slot >> 2, c = slot & 3;
            int sc = c ^ ((r >> 1) & 3);
            gl2lds16(xn  + (size_t)(row0 + r)*EMBED + k0 + sc*16, &A[slot*16]);
            gl2lds16(x2n + (size_t)(col0 + r)*EMBED + k0 + sc*16, &B[slot*16]);
        }
    };

    stage(0);                                 // 4 loads/wave in flight
    stage(1);                                 // 8 in flight

    #pragma unroll
    for (int kt = 0; kt < NKT; ++kt) {
        // counted wait: stage(kt) complete, stage(kt+1) may stay in flight
        if (kt == NKT-1) asm volatile("s_waitcnt vmcnt(0)" ::: "memory");
        else             asm volatile("s_waitcnt vmcnt(4)" ::: "memory");
        __builtin_amdgcn_s_barrier();         // buf(kt&1) globally ready

        const uchar_t* A = smem + (kt & 1) * (BM*BK + BN*BK);
        const uchar_t* B = A + BM*BK;
        #pragma unroll
        for (int s = 0; s < 2; ++s) {        // 2 k-steps of K=32
            long a[4], b[4];
            int cq = s*2 + (quad >> 1);
            int h8 = (quad & 1) * 8;
            #pragma unroll
            for (int ti = 0; ti < 4; ++ti) {
                int ra = wr*64 + ti*16 + l15;
                a[ti] = *(const long*)&A[ra*BK + ((cq ^ ((ra >> 1) & 3)) << 4) + h8];
            }
            #pragma unroll
            for (int tj = 0; tj < 4; ++tj) {
                int rb = wc*64 + tj*16 + l15;
                b[tj] = *(const long*)&B[rb*BK + ((cq ^ ((rb >> 1) & 3)) << 4) + h8];
            }
            __builtin_amdgcn_s_setprio(1);
            #pragma unroll
            for (int ti = 0; ti < 4; ++ti)
                #pragma unroll
                for (int tj = 0; tj < 4; ++tj)
                    acc[ti][tj] = __builtin_amdgcn_mfma_f32_16x16x32_fp8_fp8(a[ti], b[tj], acc[ti][tj], 0, 0, 0);
            __builtin_amdgcn_s_setprio(0);
        }
        if (kt + 2 < NKT) {
            __builtin_amdgcn_s_barrier();     // all waves done reading buf(kt&1)
            stage(kt + 2);                    // overwrite it for phase kt+2
        }
    }
    __syncthreads();                          // full drain once, before reuse

    // ---- fused single-pass epilogue ----
    float* rsum_s = (float*)smem;             // [2][BM]  indexed by wc
    float* csum_s = rsum_s + 2*BM;            // [2][BM]  indexed by wr

    bool edge = (prow == nb-1) || (pcol == nb-1);
    float csv[4] = {0.f, 0.f, 0.f, 0.f};

    if (!edge) {
        // interior: gi==gj has solutions only when wr==wc && ti==tj &&
        // l15==quad*4+r.
        bool diagb = (prow == pcol) && (wr == wc);
        #pragma unroll
        for (int ti = 0; ti < 4; ++ti) {
            #pragma unroll
            for (int r = 0; r < 4; ++r) {
                float rs = 0.f;
                #pragma unroll
                for (int tj = 0; tj < 4; ++tj) {
                    float e = __expf(acc[ti][tj][r]);
                    rs += e;
                    csv[tj] += e;
                    if (tj == ti && diagb && l15 == quad*4 + r)
                        pos[row0 + wr*64 + ti*16 + quad*4 + r] = e;
                }
                rs = dpp16_red_add(rs);
                if (l15 == 0) rsum_s[wc*BM + wr*64 + ti*16 + quad*4 + r] = rs;
            }
        }
    } else {
        #pragma unroll
        for (int ti = 0; ti < 4; ++ti) {
            #pragma unroll
            for (int r = 0; r < 4; ++r) {
                int gi = row0 + wr*64 + ti*16 + quad*4 + r;
                float rs = 0.f;
                #pragma unroll
                for (int tj = 0; tj < 4; ++tj) {
                    int gj = col0 + wc*64 + tj*16 + l15;
                    float e = 0.f;
                    if (gi < N && gj < N) {
                        e = __expf(acc[ti][tj][r]);
                        if (gi == gj) pos[gi] = e;
                    }
                    rs += e;
                    csv[tj] += e;
                }
                rs = dpp16_red_add(rs);
                if (l15 == 0) rsum_s[wc*BM + wr*64 + ti*16 + quad*4 + r] = rs;
            }
        }
    }
    #pragma unroll
    for (int tj = 0; tj < 4; ++tj) {
        float cs = csv[tj];
        cs += __shfl_xor(cs, 16, 64);
        cs += __shfl_xor(cs, 32, 64);
        if (lane < 16) csum_s[wr*BM + wc*64 + tj*16 + lane] = cs;
    }
    __syncthreads();
    if (tid < BM) {
        rowpart[(size_t)pcol*Npad + row0 + tid] = rsum_s[tid] + rsum_s[BM + tid];
        colpart[(size_t)prow*Npad + col0 + tid] = csum_s[tid] + csum_s[BM + tid];
    }
}

// ---------------- Kernel 4: log-reduction + ticket finalize -----------------
__global__ __launch_bounds__(256) void k_final(
    const float* __restrict__ rowpart, const float* __restrict__ colpart,
    const float* __restrict__ pos, const float* __restrict__ partials,
    float* __restrict__ acc3, int* __restrict__ ticket,
    float* __restrict__ out, int N, int Npad, int nb, int nparts, int M)
{
    __shared__ float red1[256], red2[256], red3[256];
    int t = threadIdx.x;
    int g = blockIdx.x * 256 + t;
    int stride = gridDim.x * 256;
    float l1 = 0.f, l2 = 0.f, mo = 0.f;
    for (int i = g; i < N; i += stride) {
        float rs = 0.f, cs = 0.f;
        for (int p = 0; p < nb; ++p) {
            rs += rowpart[(size_t)p*Npad + i];    // coalesced across threads
            cs += colpart[(size_t)p*Npad + i];
        }
        float pv = pos[i];
        l1 += __logf((cs - pv) / pv);
        l2 += __logf((rs - pv) / pv);
    }
    for (int i = g; i < nparts; i += stride) mo += partials[i];
    red1[t] = l1; red2[t] = l2; red3[t] = mo; __syncthreads();
    for (int s = 128; s > 0; s >>= 1) {
        if (t < s) { red1[t] += red1[t+s]; red2[t] += red2[t+s]; red3[t] += red3[t+s]; }
        __syncthreads();
    }
    if (t == 0) {
        atomicAdd(&acc3[0], red1[0]);
        atomicAdd(&acc3[1], red2[0]);
        atomicAdd(&acc3[2], red3[0]);
        __threadfence();                          // adds visible before ticket
        int old = atomicAdd(ticket, 1);
        if (old == (int)gridDim.x - 1) {
            float a0 = atomicAdd(&acc3[0], 0.f);
            float a1 = atomicAdd(&acc3[1], 0.f);
            float a2 = atomicAdd(&acc3[2], 0.f);
            float cl = 0.5f * (a0 + a1) / (float)N;
            out[0] = cl - a2 / (float)M;
        }
    }
}

extern "C" void kernel_launch(void* const* d_in, const int* in_sizes, int n_in,
                              void* d_out, int out_size, void* d_ws, size_t ws_size,
                              hipStream_t stream)
{
    const float* x         = (const float*)d_in[0];
    const float* feats     = (const float*)d_in[1];
    const float* feat_free = (const float*)d_in[2];
    const float* ks        = (const float*)d_in[3];
    const float* Ws        = (const float*)d_in[4];
    const float* bias      = (const float*)d_in[5];
    const float* W_free    = (const float*)d_in[6];
    const float* b_free    = (const float*)d_in[7];
    const float* W1        = (const float*)d_in[8];
    const float* b1        = (const float*)d_in[9];
    const float* W2        = (const float*)d_in[10];
    const float* b2        = (const float*)d_in[11];
    const int*   motif     = (const int*)d_in[12];
    const int*   neg_uv    = (const int*)d_in[13];
    int N = in_sizes[0] / EMBED;          // 10000
    int M = in_sizes[13] / 2;             // 50000
    int nb = (N + BM - 1) / BM;           // 79
    int Npad = nb * BM;                   // 10112

    uchar_t* xnf8  = (uchar_t*)d_ws;                       // Npad*256 fp8
    uchar_t* x2nf8 = xnf8 + (size_t)Npad*EMBED;            // Npad*256 fp8
    uchar_t* H8    = x2nf8 + (size_t)Npad*EMBED;           // 12*N*64 fp8
    float* p      = (float*)(H8 + (size_t)12*N*64);        // 3*N*32
    float* posv   = p + (size_t)3*N*32;                    // N
    float* acc3   = posv + N;                              // 3 + ticket
    int*   ticket = (int*)(acc3 + 3);
    float* partials = acc3 + 4;                            // MOTIF_BLOCKS
    float* rowpart  = partials + MOTIF_BLOCKS;             // nb*Npad
    float* colpart  = rowpart + (size_t)nb*Npad;           // nb*Npad

    k_embed<<<512, 256, 0, stream>>>(x, feats, feat_free, ks, Ws, bias,
                                     W_free, b_free, p, xnf8, x2nf8,
                                     acc3, N, Npad);
    k_mlp1<<<1024, 256, 0, stream>>>(p, feat_free, W1, b1, H8, N);
    k_fused<<<nb*nb + MOTIF_BLOCKS, 256, 0, stream>>>(xnf8, x2nf8, H8, motif, neg_uv,
                                                      W2, b2, rowpart, colpart, posv,
                                                      partials, N, Npad, nb, M);
    k_final<<<64, 256, 0, stream>>>(rowpart, colpart, posv, partials, acc3, ticket,
                                    (float*)d_out, N, Npad, nb, MOTIF_BLOCKS, M);
}